// Round 1
// baseline (4577.879 us; speedup 1.0000x reference)
//
#include <hip/hip_runtime.h>
#include <math.h>

#define NFC 32   // feature channels
#define DGC 8    // deformable groups (Cg = 4)

// ---------------- weight transpose kernels ----------------
// plain conv weight (OC, IC, 3, 3) -> wT[(ic*9+t)*OC + oc]
__global__ void k_transpose_w(const float* __restrict__ w, float* __restrict__ wT,
                              int OC, int IC) {
    int i = blockIdx.x * 256 + threadIdx.x;
    int total = OC * IC * 9;
    if (i >= total) return;
    int oc = i / (IC * 9);
    int r  = i % (IC * 9);           // ic*9 + tap
    wT[r * OC + oc] = w[i];
}

// om weight (216, 32, 3, 3) -> omT[(g*288 + ic*9+t)*27 + cl], channel = g*27+cl
__global__ void k_transpose_om(const float* __restrict__ w, float* __restrict__ wT) {
    int i = blockIdx.x * 256 + threadIdx.x;  // over 216*288
    if (i >= 216 * 288) return;
    int ch = i / 288;
    int r  = i % 288;                // ic*9 + tap
    int g = ch / 27, cl = ch % 27;
    wT[(g * 288 + r) * 27 + cl] = w[i];
}

// ---------------- generic 3x3 conv (optionally concat of two inputs) ----------------
// One thread = one output pixel, computes all 32 output channels.
// Weight indices are wave-uniform -> scalar loads.
template<bool LRELU>
__global__ void k_conv3x3(const float* __restrict__ in1, int C1,
                          const float* __restrict__ in2, int C2,
                          const float* __restrict__ wT,    // [(ic*9+t)*32 + oc]
                          const float* __restrict__ bias,  // [32]
                          float* __restrict__ out,
                          int B, int Hin, int Win, int Hout, int Wout, int stride) {
    int px = blockIdx.x * blockDim.x + threadIdx.x;
    int total = B * Hout * Wout;
    if (px >= total) return;
    int w = px % Wout;
    int h = (px / Wout) % Hout;
    int b = px / (Wout * Hout);

    float acc[NFC];
#pragma unroll
    for (int o = 0; o < NFC; ++o) acc[o] = 0.f;

    int h0 = h * stride - 1;
    int w0 = w * stride - 1;

    int icbase = 0;
    for (int s = 0; s < 2; ++s) {
        const float* src = (s == 0) ? in1 : in2;
        int C = (s == 0) ? C1 : C2;
        for (int ic = 0; ic < C; ++ic) {
            const float* p = src + ((size_t)(b * C + ic) * Hin) * Win;
            float win[9];
#pragma unroll
            for (int t = 0; t < 9; ++t) {
                int hy = h0 + t / 3;
                int wx = w0 + t % 3;
                bool v = (hy >= 0) & (hy < Hin) & (wx >= 0) & (wx < Win);
                win[t] = v ? p[hy * Win + wx] : 0.f;
            }
            const float* wp = wT + (size_t)(icbase + ic) * 9 * NFC;
#pragma unroll
            for (int t = 0; t < 9; ++t) {
#pragma unroll
                for (int o = 0; o < NFC; ++o)
                    acc[o] += win[t] * wp[t * NFC + o];
            }
        }
        icbase += C;
    }
#pragma unroll
    for (int o = 0; o < NFC; ++o) {
        float v = acc[o] + bias[o];
        if (LRELU) v = (v >= 0.f) ? v : 0.1f * v;
        out[((size_t)(b * NFC + o) * Hout + h) * Wout + w] = v;
    }
}

// ---------------- fused modulated deformable conv (DCN_sep) ----------------
// One thread = one output pixel. Fuses: 216-ch offset/mask conv, sigmoid,
// bilinear sampling with border-zeroing, mask, and the 32x32x3x3 main conv.
template<bool LRELU>
__global__ void k_dcn(const float* __restrict__ x,        // (B,32,H,W) sampled features
                      const float* __restrict__ off_fea,  // (B,32,H,W)
                      const float* __restrict__ omT,      // [(g*288 + ic*9+t)*27 + cl]
                      const float* __restrict__ om_b,     // [216]
                      const float* __restrict__ wmT,      // [(ic*9+t)*32 + oc]
                      const float* __restrict__ bias,     // [32]
                      float* __restrict__ out,
                      int B, int H, int W) {
    int px = blockIdx.x * blockDim.x + threadIdx.x;
    int total = B * H * W;
    if (px >= total) return;
    int w = px % W;
    int h = (px / W) % H;
    int b = px / (W * H);

    float acc[NFC];
#pragma unroll
    for (int o = 0; o < NFC; ++o) acc[o] = 0.f;

    for (int g = 0; g < DGC; ++g) {
        // ---- offset/mask conv for this group: 27 channels ----
        float om[27];
#pragma unroll
        for (int j = 0; j < 27; ++j) om[j] = 0.f;

        for (int ic = 0; ic < NFC; ++ic) {
            const float* p = off_fea + ((size_t)(b * NFC + ic) * H) * W;
            float win[9];
#pragma unroll
            for (int t = 0; t < 9; ++t) {
                int hy = h - 1 + t / 3;
                int wx = w - 1 + t % 3;
                bool v = (hy >= 0) & (hy < H) & (wx >= 0) & (wx < W);
                win[t] = v ? p[hy * W + wx] : 0.f;
            }
            const float* wp = omT + ((size_t)(g * 288 + ic * 9)) * 27;
#pragma unroll
            for (int t = 0; t < 9; ++t) {
#pragma unroll
                for (int j = 0; j < 27; ++j)
                    om[j] += win[t] * wp[t * 27 + j];
            }
        }

        // ---- 9 taps: sample + modulate + accumulate main conv ----
#pragma unroll
        for (int k = 0; k < 9; ++k) {
            float oy = om[k]      + om_b[g * 27 + k];
            float ox = om[9 + k]  + om_b[g * 27 + 9 + k];
            float mk = om[18 + k] + om_b[g * 27 + 18 + k];
            float m = 1.f / (1.f + __expf(-mk));
            float py  = oy + (float)(h + k / 3 - 1);
            float pxx = ox + (float)(w + k % 3 - 1);
            float y0f = floorf(py), x0f = floorf(pxx);
            float dy = py - y0f, dx = pxx - x0f;
            float y1f = y0f + 1.f, x1f = x0f + 1.f;
            float Hm1 = (float)(H - 1), Wm1 = (float)(W - 1);
            float vy0 = (y0f >= 0.f && y0f <= Hm1) ? 1.f : 0.f;
            float vy1 = (y1f >= 0.f && y1f <= Hm1) ? 1.f : 0.f;
            float vx0 = (x0f >= 0.f && x0f <= Wm1) ? 1.f : 0.f;
            float vx1 = (x1f >= 0.f && x1f <= Wm1) ? 1.f : 0.f;
            float w00 = (1.f - dy) * (1.f - dx) * vy0 * vx0;
            float w01 = (1.f - dy) * dx * vy0 * vx1;
            float w10 = dy * (1.f - dx) * vy1 * vx0;
            float w11 = dy * dx * vy1 * vx1;
            int y0c = (int)fminf(fmaxf(y0f, 0.f), Hm1);
            int y1c = (int)fminf(fmaxf(y1f, 0.f), Hm1);
            int x0c = (int)fminf(fmaxf(x0f, 0.f), Wm1);
            int x1c = (int)fminf(fmaxf(x1f, 0.f), Wm1);
#pragma unroll
            for (int c = 0; c < 4; ++c) {
                const float* xb = x + ((size_t)(b * NFC + g * 4 + c) * H) * W;
                float sv = w00 * xb[y0c * W + x0c] + w01 * xb[y0c * W + x1c]
                         + w10 * xb[y1c * W + x0c] + w11 * xb[y1c * W + x1c];
                float sm = sv * m;
                const float* wp = wmT + (size_t)((g * 4 + c) * 9 + k) * NFC;
#pragma unroll
                for (int o = 0; o < NFC; ++o)
                    acc[o] += sm * wp[o];
            }
        }
    }
#pragma unroll
    for (int o = 0; o < NFC; ++o) {
        float v = acc[o] + bias[o];
        if (LRELU) v = (v >= 0.f) ? v : 0.1f * v;
        out[((size_t)(b * NFC + o) * H + h) * W + w] = v;
    }
}

// ---------------- exact 2x bilinear upsample (jax.image.resize semantics) ----------------
__global__ void k_resize2x(const float* __restrict__ in, float* __restrict__ out,
                           int BC, int Hin, int Win) {
    int Hout = Hin * 2, Wout = Win * 2;
    int i = blockIdx.x * blockDim.x + threadIdx.x;
    int total = BC * Hout * Wout;
    if (i >= total) return;
    int wo = i % Wout;
    int ho = (i / Wout) % Hout;
    int bc = i / (Wout * Hout);
    float fy = 0.5f * (float)ho - 0.25f;
    float fx = 0.5f * (float)wo - 0.25f;
    float y0f = floorf(fy), x0f = floorf(fx);
    float wy1 = fy - y0f, wx1 = fx - x0f;
    int y0 = max(0, min((int)y0f, Hin - 1));
    int y1 = max(0, min((int)y0f + 1, Hin - 1));
    int x0 = max(0, min((int)x0f, Win - 1));
    int x1 = max(0, min((int)x0f + 1, Win - 1));
    const float* p = in + (size_t)bc * Hin * Win;
    float v = (1.f - wy1) * ((1.f - wx1) * p[y0 * Win + x0] + wx1 * p[y0 * Win + x1])
            + wy1 * ((1.f - wx1) * p[y1 * Win + x0] + wx1 * p[y1 * Win + x1]);
    out[i] = v;
}

#define CDIV(a, b) (((a) + (b) - 1) / (b))

extern "C" void kernel_launch(void* const* d_in, const int* in_sizes, int n_in,
                              void* d_out, int out_size, void* d_ws, size_t ws_size,
                              hipStream_t stream) {
    const float* L1_fea = (const float*)d_in[0];
    const float* L1_off = (const float*)d_in[1];
    const float* L2_off = (const float*)d_in[2];
    const float* L3_off = (const float*)d_in[3];
    const float* offset = (const float*)d_in[4];
    const float* w_l2c1 = (const float*)d_in[5];   const float* b_l2c1 = (const float*)d_in[6];
    const float* w_l2c2 = (const float*)d_in[7];   const float* b_l2c2 = (const float*)d_in[8];
    const float* w_l3c1 = (const float*)d_in[9];   const float* b_l3c1 = (const float*)d_in[10];
    const float* w_l3c2 = (const float*)d_in[11];  const float* b_l3c2 = (const float*)d_in[12];
    const float* w_l2fea = (const float*)d_in[13]; const float* b_l2fea = (const float*)d_in[14];
    const float* w_l1fea = (const float*)d_in[15]; const float* b_l1fea = (const float*)d_in[16];
    const float* l3_om_w = (const float*)d_in[17]; const float* l3_om_b = (const float*)d_in[18];
    const float* l3_w = (const float*)d_in[19];    const float* l3_b = (const float*)d_in[20];
    const float* l2_om_w = (const float*)d_in[21]; const float* l2_om_b = (const float*)d_in[22];
    const float* l2_w = (const float*)d_in[23];    const float* l2_b = (const float*)d_in[24];
    const float* l1_om_w = (const float*)d_in[25]; const float* l1_om_b = (const float*)d_in[26];
    const float* l1_w = (const float*)d_in[27];    const float* l1_b = (const float*)d_in[28];
    const float* cas_om_w = (const float*)d_in[29]; const float* cas_om_b = (const float*)d_in[30];
    const float* cas_w = (const float*)d_in[31];   const float* cas_b = (const float*)d_in[32];

    const int B = 4, H1 = 192, W1 = 192, H2 = 96, W2 = 96, H3 = 48, W3 = 48;

    float* ws = (float*)d_ws;
    size_t cur = 0;
    auto alloc = [&](size_t n) { float* p = ws + cur; cur += n; return p; };

    float* wT_l2c1  = alloc(288 * 32);
    float* wT_l2c2  = alloc(288 * 32);
    float* wT_l3c1  = alloc(288 * 32);
    float* wT_l3c2  = alloc(288 * 32);
    float* wT_l2fea = alloc(576 * 32);
    float* wT_l1fea = alloc(576 * 32);
    float* omT_l3   = alloc(216 * 288);
    float* omT_l2   = alloc(216 * 288);
    float* omT_l1   = alloc(216 * 288);
    float* omT_cas  = alloc(216 * 288);
    float* wmT_l3   = alloc(288 * 32);
    float* wmT_l2   = alloc(288 * 32);
    float* wmT_l1   = alloc(288 * 32);
    float* wmT_cas  = alloc(288 * 32);

    float* L2a     = alloc((size_t)B * 32 * H2 * W2);
    float* L2      = alloc((size_t)B * 32 * H2 * W2);
    float* L3a     = alloc((size_t)B * 32 * H3 * W3);
    float* L3      = alloc((size_t)B * 32 * H3 * W3);
    float* L3f     = alloc((size_t)B * 32 * H3 * W3);
    float* L2f_pre = alloc((size_t)B * 32 * H2 * W2);
    float* L3u     = alloc((size_t)B * 32 * H2 * W2);
    float* L2f     = alloc((size_t)B * 32 * H2 * W2);
    float* L1f_pre = alloc((size_t)B * 32 * H1 * W1);
    float* L2u     = alloc((size_t)B * 32 * H1 * W1);
    float* L1f     = alloc((size_t)B * 32 * H1 * W1);

    // ---- weight transposes ----
    k_transpose_w<<<CDIV(32 * 32 * 9, 256), 256, 0, stream>>>(w_l2c1, wT_l2c1, 32, 32);
    k_transpose_w<<<CDIV(32 * 32 * 9, 256), 256, 0, stream>>>(w_l2c2, wT_l2c2, 32, 32);
    k_transpose_w<<<CDIV(32 * 32 * 9, 256), 256, 0, stream>>>(w_l3c1, wT_l3c1, 32, 32);
    k_transpose_w<<<CDIV(32 * 32 * 9, 256), 256, 0, stream>>>(w_l3c2, wT_l3c2, 32, 32);
    k_transpose_w<<<CDIV(32 * 64 * 9, 256), 256, 0, stream>>>(w_l2fea, wT_l2fea, 32, 64);
    k_transpose_w<<<CDIV(32 * 64 * 9, 256), 256, 0, stream>>>(w_l1fea, wT_l1fea, 32, 64);
    k_transpose_om<<<CDIV(216 * 288, 256), 256, 0, stream>>>(l3_om_w, omT_l3);
    k_transpose_om<<<CDIV(216 * 288, 256), 256, 0, stream>>>(l2_om_w, omT_l2);
    k_transpose_om<<<CDIV(216 * 288, 256), 256, 0, stream>>>(l1_om_w, omT_l1);
    k_transpose_om<<<CDIV(216 * 288, 256), 256, 0, stream>>>(cas_om_w, omT_cas);
    k_transpose_w<<<CDIV(32 * 32 * 9, 256), 256, 0, stream>>>(l3_w, wmT_l3, 32, 32);
    k_transpose_w<<<CDIV(32 * 32 * 9, 256), 256, 0, stream>>>(l2_w, wmT_l2, 32, 32);
    k_transpose_w<<<CDIV(32 * 32 * 9, 256), 256, 0, stream>>>(l1_w, wmT_l1, 32, 32);
    k_transpose_w<<<CDIV(32 * 32 * 9, 256), 256, 0, stream>>>(cas_w, wmT_cas, 32, 32);

    // ---- feature pyramid ----
    k_conv3x3<true><<<CDIV(B * H2 * W2, 256), 256, 0, stream>>>(
        L1_fea, 32, nullptr, 0, wT_l2c1, b_l2c1, L2a, B, H1, W1, H2, W2, 2);
    k_conv3x3<true><<<CDIV(B * H2 * W2, 256), 256, 0, stream>>>(
        L2a, 32, nullptr, 0, wT_l2c2, b_l2c2, L2, B, H2, W2, H2, W2, 1);
    k_conv3x3<true><<<CDIV(B * H3 * W3, 256), 256, 0, stream>>>(
        L2, 32, nullptr, 0, wT_l3c1, b_l3c1, L3a, B, H2, W2, H3, W3, 2);
    k_conv3x3<true><<<CDIV(B * H3 * W3, 256), 256, 0, stream>>>(
        L3a, 32, nullptr, 0, wT_l3c2, b_l3c2, L3, B, H3, W3, H3, W3, 1);

    // ---- L3: dcn + lrelu ----
    k_dcn<true><<<CDIV(B * H3 * W3, 256), 256, 0, stream>>>(
        L3, L3_off, omT_l3, l3_om_b, wmT_l3, l3_b, L3f, B, H3, W3);

    // ---- L2: dcn (no act), upsample L3f, fuse ----
    k_dcn<false><<<CDIV(B * H2 * W2, 256), 256, 0, stream>>>(
        L2, L2_off, omT_l2, l2_om_b, wmT_l2, l2_b, L2f_pre, B, H2, W2);
    k_resize2x<<<CDIV(B * 32 * H2 * W2, 256), 256, 0, stream>>>(L3f, L3u, B * 32, H3, W3);
    k_conv3x3<true><<<CDIV(B * H2 * W2, 256), 256, 0, stream>>>(
        L2f_pre, 32, L3u, 32, wT_l2fea, b_l2fea, L2f, B, H2, W2, H2, W2, 1);

    // ---- L1: dcn (no act), upsample L2f, fuse (no act) ----
    k_dcn<false><<<CDIV(B * H1 * W1, 256), 256, 0, stream>>>(
        L1_fea, L1_off, omT_l1, l1_om_b, wmT_l1, l1_b, L1f_pre, B, H1, W1);
    k_resize2x<<<CDIV(B * 32 * H1 * W1, 256), 256, 0, stream>>>(L2f, L2u, B * 32, H2, W2);
    k_conv3x3<false><<<CDIV(B * H1 * W1, 256), 256, 0, stream>>>(
        L1f_pre, 32, L2u, 32, wT_l1fea, b_l1fea, L1f, B, H1, W1, H1, W1, 1);

    // ---- cascading dcn + lrelu -> output ----
    k_dcn<true><<<CDIV(B * H1 * W1, 256), 256, 0, stream>>>(
        L1f, offset, omT_cas, cas_om_b, wmT_cas, cas_b, (float*)d_out, B, H1, W1);
}

// Round 2
// 3771.288 us; speedup vs baseline: 1.2139x; 1.2139x over previous
//
#include <hip/hip_runtime.h>
#include <math.h>

#define NFC 32   // feature channels
#define DGC 8    // deformable groups (Cg = 4)
#define TPX 32   // pixels per tile (along W)

#define CDIV(a, b) (((a) + (b) - 1) / (b))

// ---------------- weight transpose kernels ----------------
// plain conv weight (OC, IC, 3, 3) -> wT[(ic*9+t)*OC + oc]
__global__ void k_transpose_w(const float* __restrict__ w, float* __restrict__ wT,
                              int OC, int IC) {
    int i = blockIdx.x * 256 + threadIdx.x;
    int total = OC * IC * 9;
    if (i >= total) return;
    int oc = i / (IC * 9);
    int r  = i % (IC * 9);           // ic*9 + tap
    wT[r * OC + oc] = w[i];
}

// om weight (216, 32, 3, 3) -> omT[(g*288 + r)*28 + j], j = s*9+k (27 used, 1 pad)
// channel ch = g*27 + j. Pad j=27 zeroed.
__global__ void k_transpose_om(const float* __restrict__ w, float* __restrict__ wT) {
    int i = blockIdx.x * 256 + threadIdx.x;  // over 216*288
    if (i >= 216 * 288) return;
    int ch = i / 288;
    int r  = i % 288;                // ic*9 + tap
    int g = ch / 27, j = ch % 27;
    wT[((size_t)g * 288 + r) * 28 + j] = w[i];
    if (j == 0) wT[((size_t)g * 288 + r) * 28 + 27] = 0.f;  // zero pad once
}

// ---------------- LDS-tiled 3x3 conv (optionally concat of two inputs) ----------------
// Block = 256 threads = 8 oc-quads x 32 pixels (one row-tile of TPX output px).
// Input windows staged in LDS once per block; weights read as float4 (L1/L2-cached).
template<bool LRELU, int CTOT, int STRIDE>
__global__ __launch_bounds__(256)
void k_conv_tile(const float* __restrict__ in1, int C1,
                 const float* __restrict__ in2,
                 const float* __restrict__ wT,    // [(ic*9+t)*32 + oc]
                 const float* __restrict__ bias,  // [32]
                 float* __restrict__ out,
                 int B, int Hin, int Win, int Hout, int Wout) {
    const int NCOL = TPX * STRIDE + 2;
    __shared__ float s_win[CTOT][3][NCOL];

    int tilesW = CDIV(Wout, TPX);
    int bid = blockIdx.x;
    int wt = bid % tilesW;
    int h  = (bid / tilesW) % Hout;
    int b  = bid / (tilesW * Hout);
    int w0 = wt * TPX;

    int tid = threadIdx.x;
    // ---- stage input windows ----
    for (int i = tid; i < CTOT * 3 * NCOL; i += 256) {
        int col = i % NCOL;
        int row = (i / NCOL) % 3;
        int ic  = i / (3 * NCOL);
        int hy = h * STRIDE - 1 + row;
        int wx = w0 * STRIDE - 1 + col;
        float v = 0.f;
        if (hy >= 0 && hy < Hin && wx >= 0 && wx < Win) {
            if (ic < C1)
                v = in1[((size_t)(b * C1 + ic) * Hin + hy) * Win + wx];
            else
                v = in2[((size_t)(b * (CTOT - C1) + (ic - C1)) * Hin + hy) * Win + wx];
        }
        s_win[ic][row][col] = v;
    }
    __syncthreads();

    int px  = tid & 31;
    int oc0 = (tid >> 5) * 4;
    int w   = w0 + px;
    if (w >= Wout) return;

    float a0 = 0.f, a1 = 0.f, a2 = 0.f, a3 = 0.f;
    for (int ic = 0; ic < CTOT; ++ic) {
        float win[9];
#pragma unroll
        for (int t = 0; t < 9; ++t)
            win[t] = s_win[ic][t / 3][px * STRIDE + t % 3];
#pragma unroll
        for (int t = 0; t < 9; ++t) {
            float4 wv = *(const float4*)(wT + (size_t)(ic * 9 + t) * 32 + oc0);
            a0 += win[t] * wv.x;
            a1 += win[t] * wv.y;
            a2 += win[t] * wv.z;
            a3 += win[t] * wv.w;
        }
    }
    float acc[4] = {a0, a1, a2, a3};
#pragma unroll
    for (int q = 0; q < 4; ++q) {
        float v = acc[q] + bias[oc0 + q];
        if (LRELU) v = (v >= 0.f) ? v : 0.1f * v;
        out[((size_t)(b * NFC + oc0 + q) * Hout + h) * Wout + w] = v;
    }
}

// ---------------- fused modulated deformable conv (DCN_sep), LDS-tiled ----------------
// Block = 256 threads. Phase 1: thread = (pixel, group): 27-ch om conv from LDS-staged
// off_fea windows + bilinear sampling + modulation -> s_samp[288][TPX]. Phase 2:
// thread = (pixel, oc-quad): 32-ch main conv as K=288 dot from LDS.
template<bool LRELU>
__global__ __launch_bounds__(256)
void k_dcn_fused(const float* __restrict__ x,        // (B,32,H,W) sampled features
                 const float* __restrict__ off_fea,  // (B,32,H,W)
                 const float* __restrict__ omT,      // [(g*288 + r)*28 + j]
                 const float* __restrict__ om_b,     // [216]
                 const float* __restrict__ wmT,      // [r*32 + oc]
                 const float* __restrict__ bias,     // [32]
                 float* __restrict__ out,
                 int B, int H, int W) {
    __shared__ float s_off[NFC][3][TPX + 2];   // 13056 B
    __shared__ float s_samp[288][TPX + 1];     // 38016 B

    int tilesW = CDIV(W, TPX);
    int bid = blockIdx.x;
    int wt = bid % tilesW;
    int h  = (bid / tilesW) % H;
    int b  = bid / (tilesW * H);
    int w0 = wt * TPX;

    int tid = threadIdx.x;
    // ---- stage off_fea windows (shared by all 8 groups) ----
    for (int i = tid; i < NFC * 3 * (TPX + 2); i += 256) {
        int col = i % (TPX + 2);
        int row = (i / (TPX + 2)) % 3;
        int ic  = i / (3 * (TPX + 2));
        int hy = h - 1 + row;
        int wx = w0 - 1 + col;
        float v = 0.f;
        if (hy >= 0 && hy < H && wx >= 0 && wx < W)
            v = off_fea[((size_t)(b * NFC + ic) * H + hy) * W + wx];
        s_off[ic][row][col] = v;
    }
    __syncthreads();

    int px = tid & 31;
    int g  = tid >> 5;
    int w  = w0 + px;
    bool active = (w < W);

    // ---- phase 1: om conv (27 channels for group g) ----
    float om[27];
#pragma unroll
    for (int j = 0; j < 27; ++j) om[j] = 0.f;

    const float* omg = omT + (size_t)g * 288 * 28;
    for (int ic = 0; ic < NFC; ++ic) {
        float win[9];
#pragma unroll
        for (int t = 0; t < 9; ++t)
            win[t] = s_off[ic][t / 3][px + t % 3];
        const float* wr = omg + ic * 9 * 28;
#pragma unroll
        for (int t = 0; t < 9; ++t) {
            const float4* wp4 = (const float4*)(wr + t * 28);
            float wv = win[t];
#pragma unroll
            for (int q = 0; q < 6; ++q) {
                float4 f = wp4[q];
                om[q * 4 + 0] += wv * f.x;
                om[q * 4 + 1] += wv * f.y;
                om[q * 4 + 2] += wv * f.z;
                om[q * 4 + 3] += wv * f.w;
            }
            float4 f = wp4[6];
            om[24] += wv * f.x;
            om[25] += wv * f.y;
            om[26] += wv * f.z;
        }
    }

    // ---- sampling + modulation -> s_samp ----
    if (active) {
        float Hm1 = (float)(H - 1), Wm1 = (float)(W - 1);
#pragma unroll
        for (int k = 0; k < 9; ++k) {
            float oy = om[k]      + om_b[g * 27 + k];
            float ox = om[9 + k]  + om_b[g * 27 + 9 + k];
            float mk = om[18 + k] + om_b[g * 27 + 18 + k];
            float m = 1.f / (1.f + __expf(-mk));
            float py  = oy + (float)(h + k / 3 - 1);
            float pxx = ox + (float)(w + k % 3 - 1);
            float y0f = floorf(py), x0f = floorf(pxx);
            float dy = py - y0f, dx = pxx - x0f;
            float y1f = y0f + 1.f, x1f = x0f + 1.f;
            float vy0 = (y0f >= 0.f && y0f <= Hm1) ? 1.f : 0.f;
            float vy1 = (y1f >= 0.f && y1f <= Hm1) ? 1.f : 0.f;
            float vx0 = (x0f >= 0.f && x0f <= Wm1) ? 1.f : 0.f;
            float vx1 = (x1f >= 0.f && x1f <= Wm1) ? 1.f : 0.f;
            float w00 = (1.f - dy) * (1.f - dx) * vy0 * vx0;
            float w01 = (1.f - dy) * dx * vy0 * vx1;
            float w10 = dy * (1.f - dx) * vy1 * vx0;
            float w11 = dy * dx * vy1 * vx1;
            int y0c = (int)fminf(fmaxf(y0f, 0.f), Hm1);
            int y1c = (int)fminf(fmaxf(y1f, 0.f), Hm1);
            int x0c = (int)fminf(fmaxf(x0f, 0.f), Wm1);
            int x1c = (int)fminf(fmaxf(x1f, 0.f), Wm1);
#pragma unroll
            for (int c = 0; c < 4; ++c) {
                const float* xb = x + ((size_t)(b * NFC + g * 4 + c) * H) * W;
                float sv = w00 * xb[y0c * W + x0c] + w01 * xb[y0c * W + x1c]
                         + w10 * xb[y1c * W + x0c] + w11 * xb[y1c * W + x1c];
                s_samp[g * 36 + c * 9 + k][px] = sv * m;
            }
        }
    }
    __syncthreads();

    // ---- phase 2: main conv, thread = (px, oc-quad), K = 288 ----
    if (!active) return;
    int oc0 = g * 4;   // reuse tid>>5 as oc-quad index
    float a0 = 0.f, a1 = 0.f, a2 = 0.f, a3 = 0.f;
    for (int j = 0; j < 288; ++j) {
        float s = s_samp[j][px];
        float4 wv = *(const float4*)(wmT + (size_t)j * 32 + oc0);
        a0 += s * wv.x;
        a1 += s * wv.y;
        a2 += s * wv.z;
        a3 += s * wv.w;
    }
    float acc[4] = {a0, a1, a2, a3};
#pragma unroll
    for (int q = 0; q < 4; ++q) {
        float v = acc[q] + bias[oc0 + q];
        if (LRELU) v = (v >= 0.f) ? v : 0.1f * v;
        out[((size_t)(b * NFC + oc0 + q) * H + h) * W + w] = v;
    }
}

// ---------------- exact 2x bilinear upsample (jax.image.resize semantics) ----------------
__global__ void k_resize2x(const float* __restrict__ in, float* __restrict__ out,
                           int BC, int Hin, int Win) {
    int Hout = Hin * 2, Wout = Win * 2;
    int i = blockIdx.x * blockDim.x + threadIdx.x;
    int total = BC * Hout * Wout;
    if (i >= total) return;
    int wo = i % Wout;
    int ho = (i / Wout) % Hout;
    int bc = i / (Wout * Hout);
    float fy = 0.5f * (float)ho - 0.25f;
    float fx = 0.5f * (float)wo - 0.25f;
    float y0f = floorf(fy), x0f = floorf(fx);
    float wy1 = fy - y0f, wx1 = fx - x0f;
    int y0 = max(0, min((int)y0f, Hin - 1));
    int y1 = max(0, min((int)y0f + 1, Hin - 1));
    int x0 = max(0, min((int)x0f, Win - 1));
    int x1 = max(0, min((int)x0f + 1, Win - 1));
    const float* p = in + (size_t)bc * Hin * Win;
    float v = (1.f - wy1) * ((1.f - wx1) * p[y0 * Win + x0] + wx1 * p[y0 * Win + x1])
            + wy1 * ((1.f - wx1) * p[y1 * Win + x0] + wx1 * p[y1 * Win + x1]);
    out[i] = v;
}

extern "C" void kernel_launch(void* const* d_in, const int* in_sizes, int n_in,
                              void* d_out, int out_size, void* d_ws, size_t ws_size,
                              hipStream_t stream) {
    const float* L1_fea = (const float*)d_in[0];
    const float* L1_off = (const float*)d_in[1];
    const float* L2_off = (const float*)d_in[2];
    const float* L3_off = (const float*)d_in[3];
    const float* offset = (const float*)d_in[4];
    const float* w_l2c1 = (const float*)d_in[5];   const float* b_l2c1 = (const float*)d_in[6];
    const float* w_l2c2 = (const float*)d_in[7];   const float* b_l2c2 = (const float*)d_in[8];
    const float* w_l3c1 = (const float*)d_in[9];   const float* b_l3c1 = (const float*)d_in[10];
    const float* w_l3c2 = (const float*)d_in[11];  const float* b_l3c2 = (const float*)d_in[12];
    const float* w_l2fea = (const float*)d_in[13]; const float* b_l2fea = (const float*)d_in[14];
    const float* w_l1fea = (const float*)d_in[15]; const float* b_l1fea = (const float*)d_in[16];
    const float* l3_om_w = (const float*)d_in[17]; const float* l3_om_b = (const float*)d_in[18];
    const float* l3_w = (const float*)d_in[19];    const float* l3_b = (const float*)d_in[20];
    const float* l2_om_w = (const float*)d_in[21]; const float* l2_om_b = (const float*)d_in[22];
    const float* l2_w = (const float*)d_in[23];    const float* l2_b = (const float*)d_in[24];
    const float* l1_om_w = (const float*)d_in[25]; const float* l1_om_b = (const float*)d_in[26];
    const float* l1_w = (const float*)d_in[27];    const float* l1_b = (const float*)d_in[28];
    const float* cas_om_w = (const float*)d_in[29]; const float* cas_om_b = (const float*)d_in[30];
    const float* cas_w = (const float*)d_in[31];   const float* cas_b = (const float*)d_in[32];

    const int B = 4, H1 = 192, W1 = 192, H2 = 96, W2 = 96, H3 = 48, W3 = 48;

    float* ws = (float*)d_ws;
    size_t cur = 0;
    auto alloc = [&](size_t n) { float* p = ws + cur; cur += n; return p; };

    float* wT_l2c1  = alloc(288 * 32);
    float* wT_l2c2  = alloc(288 * 32);
    float* wT_l3c1  = alloc(288 * 32);
    float* wT_l3c2  = alloc(288 * 32);
    float* wT_l2fea = alloc(576 * 32);
    float* wT_l1fea = alloc(576 * 32);
    float* omT_l3   = alloc(8 * 288 * 28);
    float* omT_l2   = alloc(8 * 288 * 28);
    float* omT_l1   = alloc(8 * 288 * 28);
    float* omT_cas  = alloc(8 * 288 * 28);
    float* wmT_l3   = alloc(288 * 32);
    float* wmT_l2   = alloc(288 * 32);
    float* wmT_l1   = alloc(288 * 32);
    float* wmT_cas  = alloc(288 * 32);

    float* L2a     = alloc((size_t)B * 32 * H2 * W2);
    float* L2      = alloc((size_t)B * 32 * H2 * W2);
    float* L3a     = alloc((size_t)B * 32 * H3 * W3);
    float* L3      = alloc((size_t)B * 32 * H3 * W3);
    float* L3f     = alloc((size_t)B * 32 * H3 * W3);
    float* L2f_pre = alloc((size_t)B * 32 * H2 * W2);
    float* L3u     = alloc((size_t)B * 32 * H2 * W2);
    float* L2f     = alloc((size_t)B * 32 * H2 * W2);
    float* L1f_pre = alloc((size_t)B * 32 * H1 * W1);
    float* L2u     = alloc((size_t)B * 32 * H1 * W1);
    float* L1f     = alloc((size_t)B * 32 * H1 * W1);

    // ---- weight transposes ----
    k_transpose_w<<<CDIV(32 * 32 * 9, 256), 256, 0, stream>>>(w_l2c1, wT_l2c1, 32, 32);
    k_transpose_w<<<CDIV(32 * 32 * 9, 256), 256, 0, stream>>>(w_l2c2, wT_l2c2, 32, 32);
    k_transpose_w<<<CDIV(32 * 32 * 9, 256), 256, 0, stream>>>(w_l3c1, wT_l3c1, 32, 32);
    k_transpose_w<<<CDIV(32 * 32 * 9, 256), 256, 0, stream>>>(w_l3c2, wT_l3c2, 32, 32);
    k_transpose_w<<<CDIV(32 * 64 * 9, 256), 256, 0, stream>>>(w_l2fea, wT_l2fea, 32, 64);
    k_transpose_w<<<CDIV(32 * 64 * 9, 256), 256, 0, stream>>>(w_l1fea, wT_l1fea, 32, 64);
    k_transpose_om<<<CDIV(216 * 288, 256), 256, 0, stream>>>(l3_om_w, omT_l3);
    k_transpose_om<<<CDIV(216 * 288, 256), 256, 0, stream>>>(l2_om_w, omT_l2);
    k_transpose_om<<<CDIV(216 * 288, 256), 256, 0, stream>>>(l1_om_w, omT_l1);
    k_transpose_om<<<CDIV(216 * 288, 256), 256, 0, stream>>>(cas_om_w, omT_cas);
    k_transpose_w<<<CDIV(32 * 32 * 9, 256), 256, 0, stream>>>(l3_w, wmT_l3, 32, 32);
    k_transpose_w<<<CDIV(32 * 32 * 9, 256), 256, 0, stream>>>(l2_w, wmT_l2, 32, 32);
    k_transpose_w<<<CDIV(32 * 32 * 9, 256), 256, 0, stream>>>(l1_w, wmT_l1, 32, 32);
    k_transpose_w<<<CDIV(32 * 32 * 9, 256), 256, 0, stream>>>(cas_w, wmT_cas, 32, 32);

    // ---- feature pyramid ----
    k_conv_tile<true, 32, 2><<<B * H2 * CDIV(W2, TPX), 256, 0, stream>>>(
        L1_fea, 32, nullptr, wT_l2c1, b_l2c1, L2a, B, H1, W1, H2, W2);
    k_conv_tile<true, 32, 1><<<B * H2 * CDIV(W2, TPX), 256, 0, stream>>>(
        L2a, 32, nullptr, wT_l2c2, b_l2c2, L2, B, H2, W2, H2, W2);
    k_conv_tile<true, 32, 2><<<B * H3 * CDIV(W3, TPX), 256, 0, stream>>>(
        L2, 32, nullptr, wT_l3c1, b_l3c1, L3a, B, H2, W2, H3, W3);
    k_conv_tile<true, 32, 1><<<B * H3 * CDIV(W3, TPX), 256, 0, stream>>>(
        L3a, 32, nullptr, wT_l3c2, b_l3c2, L3, B, H3, W3, H3, W3);

    // ---- L3: dcn + lrelu ----
    k_dcn_fused<true><<<B * H3 * CDIV(W3, TPX), 256, 0, stream>>>(
        L3, L3_off, omT_l3, l3_om_b, wmT_l3, l3_b, L3f, B, H3, W3);

    // ---- L2: dcn (no act), upsample L3f, fuse ----
    k_dcn_fused<false><<<B * H2 * CDIV(W2, TPX), 256, 0, stream>>>(
        L2, L2_off, omT_l2, l2_om_b, wmT_l2, l2_b, L2f_pre, B, H2, W2);
    k_resize2x<<<CDIV(B * 32 * H2 * W2, 256), 256, 0, stream>>>(L3f, L3u, B * 32, H3, W3);
    k_conv_tile<true, 64, 1><<<B * H2 * CDIV(W2, TPX), 256, 0, stream>>>(
        L2f_pre, 32, L3u, wT_l2fea, b_l2fea, L2f, B, H2, W2, H2, W2);

    // ---- L1: dcn (no act), upsample L2f, fuse (no act) ----
    k_dcn_fused<false><<<B * H1 * CDIV(W1, TPX), 256, 0, stream>>>(
        L1_fea, L1_off, omT_l1, l1_om_b, wmT_l1, l1_b, L1f_pre, B, H1, W1);
    k_resize2x<<<CDIV(B * 32 * H1 * W1, 256), 256, 0, stream>>>(L2f, L2u, B * 32, H2, W2);
    k_conv_tile<false, 64, 1><<<B * H1 * CDIV(W1, TPX), 256, 0, stream>>>(
        L1f_pre, 32, L2u, wT_l1fea, b_l1fea, L1f, B, H1, W1, H1, W1);

    // ---- cascading dcn + lrelu -> output ----
    k_dcn_fused<true><<<B * H1 * CDIV(W1, TPX), 256, 0, stream>>>(
        L1f, offset, omT_cas, cas_om_b, wmT_cas, cas_b, (float*)d_out, B, H1, W1);
}

// Round 3
// 1390.056 us; speedup vs baseline: 3.2933x; 2.7130x over previous
//
#include <hip/hip_runtime.h>
#include <math.h>

#define NFC 32   // feature channels
#define DGC 8    // deformable groups (Cg = 4)
#define TPX 32   // pixels per tile (plain conv)

#define CDIV(a, b) (((a) + (b) - 1) / (b))

typedef __attribute__((ext_vector_type(8))) short bf16x8;
typedef __attribute__((ext_vector_type(4))) float f32x4;

__device__ __forceinline__ unsigned short f2bf(float f) {
    unsigned int u = __float_as_uint(f);
    u += 0x7fffu + ((u >> 16) & 1u);          // RNE
    return (unsigned short)(u >> 16);
}
__device__ __forceinline__ float bf2f(unsigned short s) {
    return __uint_as_float((unsigned int)s << 16);
}
__device__ __forceinline__ float bf_lo(unsigned int u) { return __uint_as_float(u << 16); }
__device__ __forceinline__ float bf_hi(unsigned int u) { return __uint_as_float(u & 0xffff0000u); }

// ---------------- weight transpose: (OC,IC,3,3) -> wT[(ic*9+t)*OC + oc] ----------------
__global__ void k_transpose_w(const float* __restrict__ w, float* __restrict__ wT,
                              int OC, int IC) {
    int i = blockIdx.x * 256 + threadIdx.x;
    int total = OC * IC * 9;
    if (i >= total) return;
    int oc = i / (IC * 9);
    int r  = i % (IC * 9);
    wT[r * OC + oc] = w[i];
}

// ---- om weight swizzle to MFMA B-fragment layout, bf16 ----
// wswz[((t*14+nt)*64 + lane)*8 + j] = w_om[n=nt*16+(lane&15)][ic=(lane>>4)*8+j][t]
__global__ void k_swizzle_om(const float* __restrict__ w, unsigned short* __restrict__ wswz) {
    int i = blockIdx.x * 256 + threadIdx.x;   // 9*14*64*8 = 64512
    if (i >= 9 * 14 * 64 * 8) return;
    int j  = i & 7;
    int l  = (i >> 3) & 63;
    int nt = (i >> 9) % 14;
    int t  = i / (14 * 512);
    int n  = nt * 16 + (l & 15);
    int ic = (l >> 4) * 8 + j;
    float v = (n < 216) ? w[((size_t)(n * 32 + ic)) * 9 + t] : 0.f;
    wswz[i] = f2bf(v);
}

// ---- NCHW fp32 -> NHWC bf16 ----
__global__ void k_nchw2nhwc_bf16(const float* __restrict__ in, unsigned short* __restrict__ out,
                                 int HW, int Btot) {
    int i = blockIdx.x * 256 + threadIdx.x;   // over Btot*HW*32, c fastest
    if (i >= Btot * HW * 32) return;
    int c = i & 31;
    int pxf = i >> 5;
    int b = pxf / HW;
    int hw = pxf % HW;
    out[i] = f2bf(in[((size_t)(b * 32 + c)) * HW + hw]);
}

// ---------------- LDS-tiled 3x3 conv (optionally concat of two inputs) ----------------
template<bool LRELU, int CTOT, int STRIDE>
__global__ __launch_bounds__(256)
void k_conv_tile(const float* __restrict__ in1, int C1,
                 const float* __restrict__ in2,
                 const float* __restrict__ wT,    // [(ic*9+t)*32 + oc]
                 const float* __restrict__ bias,  // [32]
                 float* __restrict__ out,
                 int B, int Hin, int Win, int Hout, int Wout) {
    const int NCOL = TPX * STRIDE + 2;
    __shared__ float s_win[CTOT][3][NCOL];

    int tilesW = CDIV(Wout, TPX);
    int bid = blockIdx.x;
    int wt = bid % tilesW;
    int h  = (bid / tilesW) % Hout;
    int b  = bid / (tilesW * Hout);
    int w0 = wt * TPX;

    int tid = threadIdx.x;
    for (int i = tid; i < CTOT * 3 * NCOL; i += 256) {
        int col = i % NCOL;
        int row = (i / NCOL) % 3;
        int ic  = i / (3 * NCOL);
        int hy = h * STRIDE - 1 + row;
        int wx = w0 * STRIDE - 1 + col;
        float v = 0.f;
        if (hy >= 0 && hy < Hin && wx >= 0 && wx < Win) {
            if (ic < C1)
                v = in1[((size_t)(b * C1 + ic) * Hin + hy) * Win + wx];
            else
                v = in2[((size_t)(b * (CTOT - C1) + (ic - C1)) * Hin + hy) * Win + wx];
        }
        s_win[ic][row][col] = v;
    }
    __syncthreads();

    int px  = tid & 31;
    int oc0 = (tid >> 5) * 4;
    int w   = w0 + px;
    if (w >= Wout) return;

    float a0 = 0.f, a1 = 0.f, a2 = 0.f, a3 = 0.f;
    for (int ic = 0; ic < CTOT; ++ic) {
        float win[9];
#pragma unroll
        for (int t = 0; t < 9; ++t)
            win[t] = s_win[ic][t / 3][px * STRIDE + t % 3];
#pragma unroll
        for (int t = 0; t < 9; ++t) {
            float4 wv = *(const float4*)(wT + (size_t)(ic * 9 + t) * 32 + oc0);
            a0 += win[t] * wv.x;
            a1 += win[t] * wv.y;
            a2 += win[t] * wv.z;
            a3 += win[t] * wv.w;
        }
    }
    float acc[4] = {a0, a1, a2, a3};
#pragma unroll
    for (int q = 0; q < 4; ++q) {
        float v = acc[q] + bias[oc0 + q];
        if (LRELU) v = (v >= 0.f) ? v : 0.1f * v;
        out[((size_t)(b * NFC + oc0 + q) * Hout + h) * Wout + w] = v;
    }
}

// ---------------- om GEMM: MFMA 16x16x32 bf16 ----------------
// One wave per m-tile of 16 consecutive pixels within a row. K = 288 (tap-major),
// N = 216 (pad 224 = 14 n-tiles). A im2col from NHWC bf16, B from swizzled weights.
// C -> om planes [ch][px] bf16.
__global__ __launch_bounds__(256)
void k_gemm_om(const unsigned short* __restrict__ offn,  // (B,H,W,32) bf16
               const unsigned short* __restrict__ wswz,  // fragment-swizzled
               unsigned short* __restrict__ om,          // [224][Npx] (216 used)
               int B, int H, int W) {
    int wid  = (blockIdx.x * 256 + threadIdx.x) >> 6;
    int lane = threadIdx.x & 63;
    int mtW = W >> 4;
    if (wid >= B * H * mtW) return;
    int mt = wid % mtW;
    int h  = (wid / mtW) % H;
    int b  = wid / (mtW * H);
    int Npx = B * H * W;
    int px0 = mt * 16;

    f32x4 acc[14];
#pragma unroll
    for (int nt = 0; nt < 14; ++nt)
#pragma unroll
        for (int r = 0; r < 4; ++r) acc[nt][r] = 0.f;

    int m  = lane & 15;     // pixel within m-tile (A rows / C rows)
    int kq = lane >> 4;     // k-chunk: ic base kq*8

    for (int t = 0; t < 9; ++t) {
        int hy = h + t / 3 - 1;
        if (hy < 0 || hy >= H) continue;           // whole-wave zero tap
        int wx = px0 + m + t % 3 - 1;
        bf16x8 a;
#pragma unroll
        for (int j = 0; j < 8; ++j) a[j] = 0;
        if (wx >= 0 && wx < W)
            a = *(const bf16x8*)(offn + (((size_t)(b * H + hy) * W + wx) << 5) + kq * 8);
        const unsigned short* wp = wswz + ((size_t)t * 14 * 64 + lane) * 8;
#pragma unroll
        for (int nt = 0; nt < 14; ++nt) {
            bf16x8 bfrag = *(const bf16x8*)(wp + (size_t)nt * 64 * 8);
            acc[nt] = __builtin_amdgcn_mfma_f32_16x16x32_bf16(a, bfrag, acc[nt], 0, 0, 0);
        }
    }

    // C layout: ch = nt*16 + (lane&15); px = px0 + (lane>>4)*4 + r  (r=0..3)
    int ch_lo = lane & 15;
    int pxb = (b * H + h) * W + px0 + (lane >> 4) * 4;
#pragma unroll
    for (int nt = 0; nt < 14; ++nt) {
        int ch = nt * 16 + ch_lo;
        if (ch < 216) {
            ushort4 v = make_ushort4(f2bf(acc[nt][0]), f2bf(acc[nt][1]),
                                     f2bf(acc[nt][2]), f2bf(acc[nt][3]));
            *(ushort4*)(om + (size_t)ch * Npx + pxb) = v;
        }
    }
}

// ---------------- sampling + main 32-oc conv (vector fp32) ----------------
// thread = output pixel. Reads om planes (bf16), gathers x from NHWC bf16 (one 8B
// load = 4 channels of a group per corner), accumulates K=288 main conv.
template<bool LRELU>
__global__ __launch_bounds__(256)
void k_sample_conv(const unsigned short* __restrict__ xn,  // (B,H,W,32) bf16
                   const unsigned short* __restrict__ om,  // [224][Npx]
                   const float* __restrict__ om_b,         // [216]
                   const float* __restrict__ wmT,          // [288][32]
                   const float* __restrict__ bias,         // [32]
                   float* __restrict__ outp,               // (B,32,H,W) fp32
                   int B, int H, int W) {
    int idx = blockIdx.x * 256 + threadIdx.x;
    int Npx = B * H * W;
    if (idx >= Npx) return;
    int w = idx % W;
    int h = (idx / W) % H;
    int b = idx / (W * H);

    float acc[32];
#pragma unroll
    for (int o = 0; o < 32; ++o) acc[o] = 0.f;

    float Hm1 = (float)(H - 1), Wm1 = (float)(W - 1);

    for (int g = 0; g < 8; ++g) {
        float om27[27];
#pragma unroll
        for (int j = 0; j < 27; ++j)
            om27[j] = bf2f(om[(size_t)(g * 27 + j) * Npx + idx]) + om_b[g * 27 + j];

        const unsigned short* xb = xn + ((size_t)b * H * W) * 32 + g * 4;

        for (int k = 0; k < 9; ++k) {
            float mval = 1.f / (1.f + __expf(-om27[18 + k]));
            float py  = om27[k]     + (float)(h + k / 3 - 1);
            float pxx = om27[9 + k] + (float)(w + k % 3 - 1);
            float y0f = floorf(py), x0f = floorf(pxx);
            float dy = py - y0f, dx = pxx - x0f;
            float y1f = y0f + 1.f, x1f = x0f + 1.f;
            float vy0 = (y0f >= 0.f && y0f <= Hm1) ? 1.f : 0.f;
            float vy1 = (y1f >= 0.f && y1f <= Hm1) ? 1.f : 0.f;
            float vx0 = (x0f >= 0.f && x0f <= Wm1) ? 1.f : 0.f;
            float vx1 = (x1f >= 0.f && x1f <= Wm1) ? 1.f : 0.f;
            float w00 = (1.f - dy) * (1.f - dx) * vy0 * vx0;
            float w01 = (1.f - dy) * dx * vy0 * vx1;
            float w10 = dy * (1.f - dx) * vy1 * vx0;
            float w11 = dy * dx * vy1 * vx1;
            int y0c = (int)fminf(fmaxf(y0f, 0.f), Hm1);
            int y1c = (int)fminf(fmaxf(y1f, 0.f), Hm1);
            int x0c = (int)fminf(fmaxf(x0f, 0.f), Wm1);
            int x1c = (int)fminf(fmaxf(x1f, 0.f), Wm1);

            uint2 u00 = *(const uint2*)(xb + ((size_t)y0c * W + x0c) * 32);
            uint2 u01 = *(const uint2*)(xb + ((size_t)y0c * W + x1c) * 32);
            uint2 u10 = *(const uint2*)(xb + ((size_t)y1c * W + x0c) * 32);
            uint2 u11 = *(const uint2*)(xb + ((size_t)y1c * W + x1c) * 32);

            float sm[4];
            sm[0] = (w00 * bf_lo(u00.x) + w01 * bf_lo(u01.x) +
                     w10 * bf_lo(u10.x) + w11 * bf_lo(u11.x)) * mval;
            sm[1] = (w00 * bf_hi(u00.x) + w01 * bf_hi(u01.x) +
                     w10 * bf_hi(u10.x) + w11 * bf_hi(u11.x)) * mval;
            sm[2] = (w00 * bf_lo(u00.y) + w01 * bf_lo(u01.y) +
                     w10 * bf_lo(u10.y) + w11 * bf_lo(u11.y)) * mval;
            sm[3] = (w00 * bf_hi(u00.y) + w01 * bf_hi(u01.y) +
                     w10 * bf_hi(u10.y) + w11 * bf_hi(u11.y)) * mval;

#pragma unroll
            for (int c = 0; c < 4; ++c) {
                const float* wr = wmT + (size_t)((g * 4 + c) * 9 + k) * 32;
                float s = sm[c];
#pragma unroll
                for (int q = 0; q < 8; ++q) {
                    float4 f = *(const float4*)(wr + q * 4);
                    acc[q * 4 + 0] += s * f.x;
                    acc[q * 4 + 1] += s * f.y;
                    acc[q * 4 + 2] += s * f.z;
                    acc[q * 4 + 3] += s * f.w;
                }
            }
        }
    }
#pragma unroll
    for (int o = 0; o < 32; ++o) {
        float v = acc[o] + bias[o];
        if (LRELU) v = (v >= 0.f) ? v : 0.1f * v;
        outp[((size_t)(b * NFC + o) * H + h) * W + w] = v;
    }
}

// ---------------- exact 2x bilinear upsample (jax.image.resize semantics) ----------------
__global__ void k_resize2x(const float* __restrict__ in, float* __restrict__ out,
                           int BC, int Hin, int Win) {
    int Hout = Hin * 2, Wout = Win * 2;
    int i = blockIdx.x * blockDim.x + threadIdx.x;
    int total = BC * Hout * Wout;
    if (i >= total) return;
    int wo = i % Wout;
    int ho = (i / Wout) % Hout;
    int bc = i / (Wout * Hout);
    float fy = 0.5f * (float)ho - 0.25f;
    float fx = 0.5f * (float)wo - 0.25f;
    float y0f = floorf(fy), x0f = floorf(fx);
    float wy1 = fy - y0f, wx1 = fx - x0f;
    int y0 = max(0, min((int)y0f, Hin - 1));
    int y1 = max(0, min((int)y0f + 1, Hin - 1));
    int x0 = max(0, min((int)x0f, Win - 1));
    int x1 = max(0, min((int)x0f + 1, Win - 1));
    const float* p = in + (size_t)bc * Hin * Win;
    float v = (1.f - wy1) * ((1.f - wx1) * p[y0 * Win + x0] + wx1 * p[y0 * Win + x1])
            + wy1 * ((1.f - wx1) * p[y1 * Win + x0] + wx1 * p[y1 * Win + x1]);
    out[i] = v;
}

extern "C" void kernel_launch(void* const* d_in, const int* in_sizes, int n_in,
                              void* d_out, int out_size, void* d_ws, size_t ws_size,
                              hipStream_t stream) {
    const float* L1_fea = (const float*)d_in[0];
    const float* L1_off = (const float*)d_in[1];
    const float* L2_off = (const float*)d_in[2];
    const float* L3_off = (const float*)d_in[3];
    const float* offset = (const float*)d_in[4];
    const float* w_l2c1 = (const float*)d_in[5];   const float* b_l2c1 = (const float*)d_in[6];
    const float* w_l2c2 = (const float*)d_in[7];   const float* b_l2c2 = (const float*)d_in[8];
    const float* w_l3c1 = (const float*)d_in[9];   const float* b_l3c1 = (const float*)d_in[10];
    const float* w_l3c2 = (const float*)d_in[11];  const float* b_l3c2 = (const float*)d_in[12];
    const float* w_l2fea = (const float*)d_in[13]; const float* b_l2fea = (const float*)d_in[14];
    const float* w_l1fea = (const float*)d_in[15]; const float* b_l1fea = (const float*)d_in[16];
    const float* l3_om_w = (const float*)d_in[17]; const float* l3_om_b = (const float*)d_in[18];
    const float* l3_w = (const float*)d_in[19];    const float* l3_b = (const float*)d_in[20];
    const float* l2_om_w = (const float*)d_in[21]; const float* l2_om_b = (const float*)d_in[22];
    const float* l2_w = (const float*)d_in[23];    const float* l2_b = (const float*)d_in[24];
    const float* l1_om_w = (const float*)d_in[25]; const float* l1_om_b = (const float*)d_in[26];
    const float* l1_w = (const float*)d_in[27];    const float* l1_b = (const float*)d_in[28];
    const float* cas_om_w = (const float*)d_in[29]; const float* cas_om_b = (const float*)d_in[30];
    const float* cas_w = (const float*)d_in[31];   const float* cas_b = (const float*)d_in[32];

    const int B = 4, H1 = 192, W1 = 192, H2 = 96, W2 = 96, H3 = 48, W3 = 48;
    const int HW1 = H1 * W1, HW2 = H2 * W2, HW3 = H3 * W3;

    char* ws = (char*)d_ws;
    size_t cur = 0;
    auto alloc = [&](size_t bytes) {
        char* p = ws + cur;
        cur += (bytes + 255) & ~(size_t)255;
        return p;
    };

    float* wT_l2c1  = (float*)alloc(288 * 32 * 4);
    float* wT_l2c2  = (float*)alloc(288 * 32 * 4);
    float* wT_l3c1  = (float*)alloc(288 * 32 * 4);
    float* wT_l3c2  = (float*)alloc(288 * 32 * 4);
    float* wT_l2fea = (float*)alloc(576 * 32 * 4);
    float* wT_l1fea = (float*)alloc(576 * 32 * 4);
    float* wmT_l3   = (float*)alloc(288 * 32 * 4);
    float* wmT_l2   = (float*)alloc(288 * 32 * 4);
    float* wmT_l1   = (float*)alloc(288 * 32 * 4);
    float* wmT_cas  = (float*)alloc(288 * 32 * 4);
    unsigned short* wswz_l3  = (unsigned short*)alloc(64512 * 2);
    unsigned short* wswz_l2  = (unsigned short*)alloc(64512 * 2);
    unsigned short* wswz_l1  = (unsigned short*)alloc(64512 * 2);
    unsigned short* wswz_cas = (unsigned short*)alloc(64512 * 2);

    unsigned short* offn_l3  = (unsigned short*)alloc((size_t)B * 32 * HW3 * 2);
    unsigned short* offn_l2  = (unsigned short*)alloc((size_t)B * 32 * HW2 * 2);
    unsigned short* offn_l1  = (unsigned short*)alloc((size_t)B * 32 * HW1 * 2);
    unsigned short* offn_cas = (unsigned short*)alloc((size_t)B * 32 * HW1 * 2);
    unsigned short* xn_l3    = (unsigned short*)alloc((size_t)B * 32 * HW3 * 2);
    unsigned short* xn_l2    = (unsigned short*)alloc((size_t)B * 32 * HW2 * 2);
    unsigned short* xn_l1    = (unsigned short*)alloc((size_t)B * 32 * HW1 * 2);
    unsigned short* xn_cas   = (unsigned short*)alloc((size_t)B * 32 * HW1 * 2);
    unsigned short* om       = (unsigned short*)alloc((size_t)224 * B * HW1 * 2);

    float* L2a     = (float*)alloc((size_t)B * 32 * HW2 * 4);
    float* L2      = (float*)alloc((size_t)B * 32 * HW2 * 4);
    float* L3a     = (float*)alloc((size_t)B * 32 * HW3 * 4);
    float* L3      = (float*)alloc((size_t)B * 32 * HW3 * 4);
    float* L3f     = (float*)alloc((size_t)B * 32 * HW3 * 4);
    float* L2f_pre = (float*)alloc((size_t)B * 32 * HW2 * 4);
    float* L3u     = (float*)alloc((size_t)B * 32 * HW2 * 4);
    float* L2f     = (float*)alloc((size_t)B * 32 * HW2 * 4);
    float* L1f_pre = (float*)alloc((size_t)B * 32 * HW1 * 4);
    float* L2u     = (float*)alloc((size_t)B * 32 * HW1 * 4);
    float* L1f     = (float*)alloc((size_t)B * 32 * HW1 * 4);

    // ---- weight prep ----
    k_transpose_w<<<CDIV(32 * 32 * 9, 256), 256, 0, stream>>>(w_l2c1, wT_l2c1, 32, 32);
    k_transpose_w<<<CDIV(32 * 32 * 9, 256), 256, 0, stream>>>(w_l2c2, wT_l2c2, 32, 32);
    k_transpose_w<<<CDIV(32 * 32 * 9, 256), 256, 0, stream>>>(w_l3c1, wT_l3c1, 32, 32);
    k_transpose_w<<<CDIV(32 * 32 * 9, 256), 256, 0, stream>>>(w_l3c2, wT_l3c2, 32, 32);
    k_transpose_w<<<CDIV(32 * 64 * 9, 256), 256, 0, stream>>>(w_l2fea, wT_l2fea, 32, 64);
    k_transpose_w<<<CDIV(32 * 64 * 9, 256), 256, 0, stream>>>(w_l1fea, wT_l1fea, 32, 64);
    k_transpose_w<<<CDIV(32 * 32 * 9, 256), 256, 0, stream>>>(l3_w, wmT_l3, 32, 32);
    k_transpose_w<<<CDIV(32 * 32 * 9, 256), 256, 0, stream>>>(l2_w, wmT_l2, 32, 32);
    k_transpose_w<<<CDIV(32 * 32 * 9, 256), 256, 0, stream>>>(l1_w, wmT_l1, 32, 32);
    k_transpose_w<<<CDIV(32 * 32 * 9, 256), 256, 0, stream>>>(cas_w, wmT_cas, 32, 32);
    k_swizzle_om<<<CDIV(64512, 256), 256, 0, stream>>>(l3_om_w, wswz_l3);
    k_swizzle_om<<<CDIV(64512, 256), 256, 0, stream>>>(l2_om_w, wswz_l2);
    k_swizzle_om<<<CDIV(64512, 256), 256, 0, stream>>>(l1_om_w, wswz_l1);
    k_swizzle_om<<<CDIV(64512, 256), 256, 0, stream>>>(cas_om_w, wswz_cas);

    // ---- input conversions ----
    k_nchw2nhwc_bf16<<<CDIV(B * 32 * HW3, 256), 256, 0, stream>>>(L3_off, offn_l3, HW3, B);
    k_nchw2nhwc_bf16<<<CDIV(B * 32 * HW2, 256), 256, 0, stream>>>(L2_off, offn_l2, HW2, B);
    k_nchw2nhwc_bf16<<<CDIV(B * 32 * HW1, 256), 256, 0, stream>>>(L1_off, offn_l1, HW1, B);
    k_nchw2nhwc_bf16<<<CDIV(B * 32 * HW1, 256), 256, 0, stream>>>(offset, offn_cas, HW1, B);
    k_nchw2nhwc_bf16<<<CDIV(B * 32 * HW1, 256), 256, 0, stream>>>(L1_fea, xn_l1, HW1, B);

    // ---- feature pyramid ----
    k_conv_tile<true, 32, 2><<<B * H2 * CDIV(W2, TPX), 256, 0, stream>>>(
        L1_fea, 32, nullptr, wT_l2c1, b_l2c1, L2a, B, H1, W1, H2, W2);
    k_conv_tile<true, 32, 1><<<B * H2 * CDIV(W2, TPX), 256, 0, stream>>>(
        L2a, 32, nullptr, wT_l2c2, b_l2c2, L2, B, H2, W2, H2, W2);
    k_conv_tile<true, 32, 2><<<B * H3 * CDIV(W3, TPX), 256, 0, stream>>>(
        L2, 32, nullptr, wT_l3c1, b_l3c1, L3a, B, H2, W2, H3, W3);
    k_conv_tile<true, 32, 1><<<B * H3 * CDIV(W3, TPX), 256, 0, stream>>>(
        L3a, 32, nullptr, wT_l3c2, b_l3c2, L3, B, H3, W3, H3, W3);
    k_nchw2nhwc_bf16<<<CDIV(B * 32 * HW2, 256), 256, 0, stream>>>(L2, xn_l2, HW2, B);
    k_nchw2nhwc_bf16<<<CDIV(B * 32 * HW3, 256), 256, 0, stream>>>(L3, xn_l3, HW3, B);

    // ---- L3 dcn + lrelu ----
    k_gemm_om<<<CDIV(B * H3 * (W3 / 16), 4), 256, 0, stream>>>(offn_l3, wswz_l3, om, B, H3, W3);
    k_sample_conv<true><<<CDIV(B * HW3, 256), 256, 0, stream>>>(
        xn_l3, om, l3_om_b, wmT_l3, l3_b, L3f, B, H3, W3);

    // ---- L2 dcn, upsample L3f, fuse ----
    k_gemm_om<<<CDIV(B * H2 * (W2 / 16), 4), 256, 0, stream>>>(offn_l2, wswz_l2, om, B, H2, W2);
    k_sample_conv<false><<<CDIV(B * HW2, 256), 256, 0, stream>>>(
        xn_l2, om, l2_om_b, wmT_l2, l2_b, L2f_pre, B, H2, W2);
    k_resize2x<<<CDIV(B * 32 * HW2, 256), 256, 0, stream>>>(L3f, L3u, B * 32, H3, W3);
    k_conv_tile<true, 64, 1><<<B * H2 * CDIV(W2, TPX), 256, 0, stream>>>(
        L2f_pre, 32, L3u, wT_l2fea, b_l2fea, L2f, B, H2, W2, H2, W2);

    // ---- L1 dcn, upsample L2f, fuse (no act) ----
    k_gemm_om<<<CDIV(B * H1 * (W1 / 16), 4), 256, 0, stream>>>(offn_l1, wswz_l1, om, B, H1, W1);
    k_sample_conv<false><<<CDIV(B * HW1, 256), 256, 0, stream>>>(
        xn_l1, om, l1_om_b, wmT_l1, l1_b, L1f_pre, B, H1, W1);
    k_resize2x<<<CDIV(B * 32 * HW1, 256), 256, 0, stream>>>(L2f, L2u, B * 32, H2, W2);
    k_conv_tile<false, 64, 1><<<B * H1 * CDIV(W1, TPX), 256, 0, stream>>>(
        L1f_pre, 32, L2u, wT_l1fea, b_l1fea, L1f, B, H1, W1, H1, W1);
    k_nchw2nhwc_bf16<<<CDIV(B * 32 * HW1, 256), 256, 0, stream>>>(L1f, xn_cas, HW1, B);

    // ---- cascading dcn + lrelu -> output ----
    k_gemm_om<<<CDIV(B * H1 * (W1 / 16), 4), 256, 0, stream>>>(offn_cas, wswz_cas, om, B, H1, W1);
    k_sample_conv<true><<<CDIV(B * HW1, 256), 256, 0, stream>>>(
        xn_cas, om, cas_om_b, wmT_cas, cas_b, (float*)d_out, B, H1, W1);
}

// Round 4
// 904.415 us; speedup vs baseline: 5.0617x; 1.5370x over previous
//
#include <hip/hip_runtime.h>
#include <math.h>

#define NFC 32   // feature channels
#define DGC 8    // deformable groups (Cg = 4)

#define CDIV(a, b) (((a) + (b) - 1) / (b))

typedef __attribute__((ext_vector_type(8))) short bf16x8;
typedef __attribute__((ext_vector_type(4))) float f32x4;

__device__ __forceinline__ unsigned short f2bf(float f) {
    unsigned int u = __float_as_uint(f);
    u += 0x7fffu + ((u >> 16) & 1u);          // RNE
    return (unsigned short)(u >> 16);
}
__device__ __forceinline__ float bf2f(unsigned short s) {
    return __uint_as_float((unsigned int)s << 16);
}
__device__ __forceinline__ float bf_lo(unsigned int u) { return __uint_as_float(u << 16); }
__device__ __forceinline__ float bf_hi(unsigned int u) { return __uint_as_float(u & 0xffff0000u); }

// ================= weight prep (merged via gridDim.y) =================
struct Ptr4F { const float* s[4]; };
struct Ptr4U { unsigned short* d[4]; };
struct Ptr4Fd { float* d[4]; };

// om weight (216,32,3,3) -> B-fragment swizzle (bf16):
// wswz[((t*14+nt)*64 + lane)*8 + j] = w[n=nt*16+(lane&15)][ic=(lane>>4)*8+j][t]
__global__ void k_swz_om4(Ptr4F src, Ptr4U dst) {
    const float* w = src.s[blockIdx.y];
    unsigned short* o = dst.d[blockIdx.y];
    int i = blockIdx.x * 256 + threadIdx.x;   // 9*14*64*8 = 64512
    if (i >= 9 * 14 * 64 * 8) return;
    int j  = i & 7;
    int l  = (i >> 3) & 63;
    int nt = (i >> 9) % 14;
    int t  = i / (14 * 512);
    int n  = nt * 16 + (l & 15);
    int ic = (l >> 4) * 8 + j;
    float v = (n < 216) ? w[((size_t)(n * 32 + ic)) * 9 + t] : 0.f;
    o[i] = f2bf(v);
}

// conv weight (32, ICt, 3,3) -> A-fragment swizzle (bf16):
// wA[(((t*KC+ck)*2+mt)*64+lane)*8+j] = w[oc=mt*16+(lane&15)][ic=ck*32+(lane>>4)*8+j][t]
template<int ICt>
__global__ void k_swz_wA(Ptr4F src, Ptr4U dst) {
    const int KC = ICt / 32;
    const float* w = src.s[blockIdx.y];
    unsigned short* o = dst.d[blockIdx.y];
    int i = blockIdx.x * 256 + threadIdx.x;   // 9*KC*2*512
    if (i >= 9 * KC * 1024) return;
    int idx = i;
    int j = idx & 7;   idx >>= 3;
    int l = idx & 63;  idx >>= 6;
    int mt = idx & 1;  idx >>= 1;
    int ck = idx % KC; idx /= KC;
    int t = idx;
    int oc = mt * 16 + (l & 15);
    int ic = ck * 32 + (l >> 4) * 8 + j;
    o[i] = f2bf(w[((size_t)(oc * ICt + ic)) * 9 + t]);
}

// main dcn weight (32,32,3,3) -> wmT[(ic*9+t)*32 + oc] fp32 (for sampler)
__global__ void k_tp_wm4(Ptr4F src, Ptr4Fd dst) {
    const float* w = src.s[blockIdx.y];
    float* o = dst.d[blockIdx.y];
    int i = blockIdx.x * 256 + threadIdx.x;
    if (i >= 32 * 32 * 9) return;
    int oc = i / (32 * 9);
    int r  = i % (32 * 9);
    o[r * 32 + oc] = w[i];
}

// NCHW fp32 -> NHWC bf16 (merged y-layers, same HW)
__global__ void k_cvt_nhwc(Ptr4F src, Ptr4U dst, int HW, int Btot) {
    const float* in = src.s[blockIdx.y];
    unsigned short* out = dst.d[blockIdx.y];
    int i = blockIdx.x * 256 + threadIdx.x;   // over Btot*HW*32, c fastest
    if (i >= Btot * HW * 32) return;
    int c = i & 31;
    int pxf = i >> 5;
    int b = pxf / HW;
    int hw = pxf % HW;
    out[i] = f2bf(in[((size_t)(b * 32 + c)) * HW + hw]);
}

// ================= MFMA 3x3 conv, NHWC bf16 in/out =================
// wave = 16*NT output pixels x 32 oc. A = weights (M=oc), B = im2col (N=px).
// C layout: col=lane&15 = pixel, row=(lane>>4)*4+r = oc -> ushort4 NHWC store.
template<int NT, int KC, int STRIDE, bool LRELU>
__global__ __launch_bounds__(256)
void k_conv_mfma(const unsigned short* __restrict__ in1,  // NHWC bf16 32ch
                 const unsigned short* __restrict__ in2,  // NHWC bf16 32ch (KC=2) or null
                 const unsigned short* __restrict__ wA,   // A-fragment swizzled
                 const float* __restrict__ bias,          // [32]
                 unsigned short* __restrict__ out,        // NHWC bf16 32ch
                 int B, int Hin, int Win, int Hout, int Wout) {
    int wid  = (blockIdx.x * 256 + threadIdx.x) >> 6;
    int lane = threadIdx.x & 63;
    int strips = Wout / (16 * NT);
    if (wid >= B * Hout * strips) return;
    int st = wid % strips;
    int h  = (wid / strips) % Hout;
    int b  = wid / (strips * Hout);
    int px0 = st * 16 * NT;

    f32x4 acc[NT][2];
#pragma unroll
    for (int nt = 0; nt < NT; ++nt)
#pragma unroll
        for (int mt = 0; mt < 2; ++mt)
#pragma unroll
            for (int r = 0; r < 4; ++r) acc[nt][mt][r] = 0.f;

    int n  = lane & 15;
    int kq = lane >> 4;

#pragma unroll
    for (int t = 0; t < 9; ++t) {
        int hy = h * STRIDE + t / 3 - 1;
        if (hy < 0 || hy >= Hin) continue;
#pragma unroll
        for (int ck = 0; ck < KC; ++ck) {
            const unsigned short* rowp =
                ((KC == 2 && ck == 1) ? in2 : in1) + ((size_t)(b * Hin + hy) * Win) * 32;
            bf16x8 a0 = *(const bf16x8*)(wA + (size_t)((((t * KC + ck) * 2 + 0) * 64 + lane)) * 8);
            bf16x8 a1 = *(const bf16x8*)(wA + (size_t)((((t * KC + ck) * 2 + 1) * 64 + lane)) * 8);
#pragma unroll
            for (int nt = 0; nt < NT; ++nt) {
                int wx = (px0 + nt * 16 + n) * STRIDE + t % 3 - 1;
                bf16x8 bf;
#pragma unroll
                for (int j = 0; j < 8; ++j) bf[j] = 0;
                if (wx >= 0 && wx < Win)
                    bf = *(const bf16x8*)(rowp + (size_t)wx * 32 + kq * 8);
                acc[nt][0] = __builtin_amdgcn_mfma_f32_16x16x32_bf16(a0, bf, acc[nt][0], 0, 0, 0);
                acc[nt][1] = __builtin_amdgcn_mfma_f32_16x16x32_bf16(a1, bf, acc[nt][1], 0, 0, 0);
            }
        }
    }

    // store: pixel = px0 + nt*16 + (lane&15), oc = mt*16 + kq*4 + r
    size_t rowbase = ((size_t)(b * Hout + h) * Wout);
#pragma unroll
    for (int mt = 0; mt < 2; ++mt) {
        float4 bs = *(const float4*)(bias + mt * 16 + kq * 4);
#pragma unroll
        for (int nt = 0; nt < NT; ++nt) {
            int px = px0 + nt * 16 + n;
            float v0 = acc[nt][mt][0] + bs.x;
            float v1 = acc[nt][mt][1] + bs.y;
            float v2 = acc[nt][mt][2] + bs.z;
            float v3 = acc[nt][mt][3] + bs.w;
            if (LRELU) {
                v0 = (v0 >= 0.f) ? v0 : 0.1f * v0;
                v1 = (v1 >= 0.f) ? v1 : 0.1f * v1;
                v2 = (v2 >= 0.f) ? v2 : 0.1f * v2;
                v3 = (v3 >= 0.f) ? v3 : 0.1f * v3;
            }
            ushort4 sv = make_ushort4(f2bf(v0), f2bf(v1), f2bf(v2), f2bf(v3));
            *(ushort4*)(out + (rowbase + px) * 32 + mt * 16 + kq * 4) = sv;
        }
    }
}

// ================= om GEMM: MFMA 16x16x32 bf16 (unchanged structure) =================
__global__ __launch_bounds__(256)
void k_gemm_om(const unsigned short* __restrict__ offn,  // (B,H,W,32) bf16
               const unsigned short* __restrict__ wswz,  // B-fragment swizzled
               unsigned short* __restrict__ om,          // [224][Npx] (216 used)
               int B, int H, int W) {
    int wid  = (blockIdx.x * 256 + threadIdx.x) >> 6;
    int lane = threadIdx.x & 63;
    int mtW = W >> 4;
    if (wid >= B * H * mtW) return;
    int mt = wid % mtW;
    int h  = (wid / mtW) % H;
    int b  = wid / (mtW * H);
    int Npx = B * H * W;
    int px0 = mt * 16;

    f32x4 acc[14];
#pragma unroll
    for (int nt = 0; nt < 14; ++nt)
#pragma unroll
        for (int r = 0; r < 4; ++r) acc[nt][r] = 0.f;

    int m  = lane & 15;
    int kq = lane >> 4;

    for (int t = 0; t < 9; ++t) {
        int hy = h + t / 3 - 1;
        if (hy < 0 || hy >= H) continue;
        int wx = px0 + m + t % 3 - 1;
        bf16x8 a;
#pragma unroll
        for (int j = 0; j < 8; ++j) a[j] = 0;
        if (wx >= 0 && wx < W)
            a = *(const bf16x8*)(offn + (((size_t)(b * H + hy) * W + wx) << 5) + kq * 8);
        const unsigned short* wp = wswz + ((size_t)t * 14 * 64 + lane) * 8;
#pragma unroll
        for (int nt = 0; nt < 14; ++nt) {
            bf16x8 bfrag = *(const bf16x8*)(wp + (size_t)nt * 64 * 8);
            acc[nt] = __builtin_amdgcn_mfma_f32_16x16x32_bf16(a, bfrag, acc[nt], 0, 0, 0);
        }
    }

    int ch_lo = lane & 15;
    int pxb = (b * H + h) * W + px0 + (lane >> 4) * 4;
#pragma unroll
    for (int nt = 0; nt < 14; ++nt) {
        int ch = nt * 16 + ch_lo;
        if (ch < 216) {
            ushort4 v = make_ushort4(f2bf(acc[nt][0]), f2bf(acc[nt][1]),
                                     f2bf(acc[nt][2]), f2bf(acc[nt][3]));
            *(ushort4*)(om + (size_t)ch * Npx + pxb) = v;
        }
    }
}

// ================= sampling + main 32-oc conv =================
// MODE 0: NHWC bf16, no act.  MODE 1: NHWC bf16 + lrelu.  MODE 2: NCHW fp32 + lrelu.
template<int MODE>
__global__ __launch_bounds__(256)
void k_sample_conv(const unsigned short* __restrict__ xn,  // (B,H,W,32) bf16
                   const unsigned short* __restrict__ om,  // [224][Npx]
                   const float* __restrict__ om_b,         // [216]
                   const float* __restrict__ wmT,          // [288][32] fp32
                   const float* __restrict__ bias,         // [32]
                   float* __restrict__ outf,               // MODE 2
                   unsigned short* __restrict__ outb,      // MODE 0/1
                   int B, int H, int W) {
    int idx = blockIdx.x * 256 + threadIdx.x;
    int Npx = B * H * W;
    if (idx >= Npx) return;
    int w = idx % W;
    int h = (idx / W) % H;
    int b = idx / (W * H);

    float acc[32];
#pragma unroll
    for (int o = 0; o < 32; ++o) acc[o] = 0.f;

    float Hm1 = (float)(H - 1), Wm1 = (float)(W - 1);

    for (int g = 0; g < 8; ++g) {
        float om27[27];
#pragma unroll
        for (int j = 0; j < 27; ++j)
            om27[j] = bf2f(om[(size_t)(g * 27 + j) * Npx + idx]) + om_b[g * 27 + j];

        const unsigned short* xb = xn + ((size_t)b * H * W) * 32 + g * 4;

        for (int k = 0; k < 9; ++k) {
            float mval = 1.f / (1.f + __expf(-om27[18 + k]));
            float py  = om27[k]     + (float)(h + k / 3 - 1);
            float pxx = om27[9 + k] + (float)(w + k % 3 - 1);
            float y0f = floorf(py), x0f = floorf(pxx);
            float dy = py - y0f, dx = pxx - x0f;
            float y1f = y0f + 1.f, x1f = x0f + 1.f;
            float vy0 = (y0f >= 0.f && y0f <= Hm1) ? 1.f : 0.f;
            float vy1 = (y1f >= 0.f && y1f <= Hm1) ? 1.f : 0.f;
            float vx0 = (x0f >= 0.f && x0f <= Wm1) ? 1.f : 0.f;
            float vx1 = (x1f >= 0.f && x1f <= Wm1) ? 1.f : 0.f;
            float w00 = (1.f - dy) * (1.f - dx) * vy0 * vx0;
            float w01 = (1.f - dy) * dx * vy0 * vx1;
            float w10 = dy * (1.f - dx) * vy1 * vx0;
            float w11 = dy * dx * vy1 * vx1;
            int y0c = (int)fminf(fmaxf(y0f, 0.f), Hm1);
            int y1c = (int)fminf(fmaxf(y1f, 0.f), Hm1);
            int x0c = (int)fminf(fmaxf(x0f, 0.f), Wm1);
            int x1c = (int)fminf(fmaxf(x1f, 0.f), Wm1);

            uint2 u00 = *(const uint2*)(xb + ((size_t)y0c * W + x0c) * 32);
            uint2 u01 = *(const uint2*)(xb + ((size_t)y0c * W + x1c) * 32);
            uint2 u10 = *(const uint2*)(xb + ((size_t)y1c * W + x0c) * 32);
            uint2 u11 = *(const uint2*)(xb + ((size_t)y1c * W + x1c) * 32);

            float sm[4];
            sm[0] = (w00 * bf_lo(u00.x) + w01 * bf_lo(u01.x) +
                     w10 * bf_lo(u10.x) + w11 * bf_lo(u11.x)) * mval;
            sm[1] = (w00 * bf_hi(u00.x) + w01 * bf_hi(u01.x) +
                     w10 * bf_hi(u10.x) + w11 * bf_hi(u11.x)) * mval;
            sm[2] = (w00 * bf_lo(u00.y) + w01 * bf_lo(u01.y) +
                     w10 * bf_lo(u10.y) + w11 * bf_lo(u11.y)) * mval;
            sm[3] = (w00 * bf_hi(u00.y) + w01 * bf_hi(u01.y) +
                     w10 * bf_hi(u10.y) + w11 * bf_hi(u11.y)) * mval;

#pragma unroll
            for (int c = 0; c < 4; ++c) {
                const float* wr = wmT + (size_t)((g * 4 + c) * 9 + k) * 32;
                float s = sm[c];
#pragma unroll
                for (int q = 0; q < 8; ++q) {
                    float4 f = *(const float4*)(wr + q * 4);
                    acc[q * 4 + 0] += s * f.x;
                    acc[q * 4 + 1] += s * f.y;
                    acc[q * 4 + 2] += s * f.z;
                    acc[q * 4 + 3] += s * f.w;
                }
            }
        }
    }

    if (MODE == 2) {
#pragma unroll
        for (int o = 0; o < 32; ++o) {
            float v = acc[o] + bias[o];
            v = (v >= 0.f) ? v : 0.1f * v;
            outf[((size_t)(b * NFC + o) * H + h) * W + w] = v;
        }
    } else {
        unsigned int packed[16];
#pragma unroll
        for (int o = 0; o < 16; ++o) {
            float v0 = acc[2 * o] + bias[2 * o];
            float v1 = acc[2 * o + 1] + bias[2 * o + 1];
            if (MODE == 1) {
                v0 = (v0 >= 0.f) ? v0 : 0.1f * v0;
                v1 = (v1 >= 0.f) ? v1 : 0.1f * v1;
            }
            packed[o] = (unsigned int)f2bf(v0) | ((unsigned int)f2bf(v1) << 16);
        }
        uint4* dst = (uint4*)(outb + (size_t)idx * 32);
#pragma unroll
        for (int q = 0; q < 4; ++q)
            dst[q] = make_uint4(packed[q * 4], packed[q * 4 + 1],
                                packed[q * 4 + 2], packed[q * 4 + 3]);
    }
}

// ================= exact 2x bilinear upsample, NHWC bf16 =================
__global__ void k_resize2x_nhwc(const unsigned short* __restrict__ in,
                                unsigned short* __restrict__ out,
                                int B, int Hin, int Win) {
    int Hout = Hin * 2, Wout = Win * 2;
    int i = blockIdx.x * 256 + threadIdx.x;     // (b,ho,wo,q) q=ch-octet
    int total = B * Hout * Wout * 4;
    if (i >= total) return;
    int q  = i & 3;
    int wo = (i >> 2) % Wout;
    int ho = (i >> 2) / Wout % Hout;
    int b  = (i >> 2) / (Wout * Hout);
    float fy = 0.5f * (float)ho - 0.25f;
    float fx = 0.5f * (float)wo - 0.25f;
    float y0f = floorf(fy), x0f = floorf(fx);
    float wy1 = fy - y0f, wx1 = fx - x0f;
    int y0 = max(0, min((int)y0f, Hin - 1));
    int y1 = max(0, min((int)y0f + 1, Hin - 1));
    int x0 = max(0, min((int)x0f, Win - 1));
    int x1 = max(0, min((int)x0f + 1, Win - 1));
    const unsigned short* base = in + ((size_t)b * Hin * Win) * 32 + q * 8;
    const uint4 u00 = *(const uint4*)(base + ((size_t)y0 * Win + x0) * 32);
    const uint4 u01 = *(const uint4*)(base + ((size_t)y0 * Win + x1) * 32);
    const uint4 u10 = *(const uint4*)(base + ((size_t)y1 * Win + x0) * 32);
    const uint4 u11 = *(const uint4*)(base + ((size_t)y1 * Win + x1) * 32);
    float c00 = (1.f - wy1) * (1.f - wx1), c01 = (1.f - wy1) * wx1;
    float c10 = wy1 * (1.f - wx1), c11 = wy1 * wx1;
    const unsigned int* p00 = (const unsigned int*)&u00;
    const unsigned int* p01 = (const unsigned int*)&u01;
    const unsigned int* p10 = (const unsigned int*)&u10;
    const unsigned int* p11 = (const unsigned int*)&u11;
    unsigned int packed[4];
#pragma unroll
    for (int d = 0; d < 4; ++d) {
        float lo = c00 * bf_lo(p00[d]) + c01 * bf_lo(p01[d]) +
                   c10 * bf_lo(p10[d]) + c11 * bf_lo(p11[d]);
        float hi = c00 * bf_hi(p00[d]) + c01 * bf_hi(p01[d]) +
                   c10 * bf_hi(p10[d]) + c11 * bf_hi(p11[d]);
        packed[d] = (unsigned int)f2bf(lo) | ((unsigned int)f2bf(hi) << 16);
    }
    *(uint4*)(out + ((size_t)(b * Hout + ho) * Wout + wo) * 32 + q * 8) =
        make_uint4(packed[0], packed[1], packed[2], packed[3]);
}

extern "C" void kernel_launch(void* const* d_in, const int* in_sizes, int n_in,
                              void* d_out, int out_size, void* d_ws, size_t ws_size,
                              hipStream_t stream) {
    const float* L1_fea = (const float*)d_in[0];
    const float* L1_off = (const float*)d_in[1];
    const float* L2_off = (const float*)d_in[2];
    const float* L3_off = (const float*)d_in[3];
    const float* offset = (const float*)d_in[4];
    const float* w_l2c1 = (const float*)d_in[5];   const float* b_l2c1 = (const float*)d_in[6];
    const float* w_l2c2 = (const float*)d_in[7];   const float* b_l2c2 = (const float*)d_in[8];
    const float* w_l3c1 = (const float*)d_in[9];   const float* b_l3c1 = (const float*)d_in[10];
    const float* w_l3c2 = (const float*)d_in[11];  const float* b_l3c2 = (const float*)d_in[12];
    const float* w_l2fea = (const float*)d_in[13]; const float* b_l2fea = (const float*)d_in[14];
    const float* w_l1fea = (const float*)d_in[15]; const float* b_l1fea = (const float*)d_in[16];
    const float* l3_om_w = (const float*)d_in[17]; const float* l3_om_b = (const float*)d_in[18];
    const float* l3_w = (const float*)d_in[19];    const float* l3_b = (const float*)d_in[20];
    const float* l2_om_w = (const float*)d_in[21]; const float* l2_om_b = (const float*)d_in[22];
    const float* l2_w = (const float*)d_in[23];    const float* l2_b = (const float*)d_in[24];
    const float* l1_om_w = (const float*)d_in[25]; const float* l1_om_b = (const float*)d_in[26];
    const float* l1_w = (const float*)d_in[27];    const float* l1_b = (const float*)d_in[28];
    const float* cas_om_w = (const float*)d_in[29]; const float* cas_om_b = (const float*)d_in[30];
    const float* cas_w = (const float*)d_in[31];   const float* cas_b = (const float*)d_in[32];

    const int B = 4, H1 = 192, W1 = 192, H2 = 96, W2 = 96, H3 = 48, W3 = 48;
    const int HW1 = H1 * W1, HW2 = H2 * W2, HW3 = H3 * W3;

    char* ws = (char*)d_ws;
    size_t cur = 0;
    auto alloc = [&](size_t bytes) {
        char* p = ws + cur;
        cur += (bytes + 255) & ~(size_t)255;
        return p;
    };

    // weight buffers
    unsigned short* wA_l2c1  = (unsigned short*)alloc(9216 * 2);
    unsigned short* wA_l2c2  = (unsigned short*)alloc(9216 * 2);
    unsigned short* wA_l3c1  = (unsigned short*)alloc(9216 * 2);
    unsigned short* wA_l3c2  = (unsigned short*)alloc(9216 * 2);
    unsigned short* wA_l2fea = (unsigned short*)alloc(18432 * 2);
    unsigned short* wA_l1fea = (unsigned short*)alloc(18432 * 2);
    float* wmT_l3   = (float*)alloc(288 * 32 * 4);
    float* wmT_l2   = (float*)alloc(288 * 32 * 4);
    float* wmT_l1   = (float*)alloc(288 * 32 * 4);
    float* wmT_cas  = (float*)alloc(288 * 32 * 4);
    unsigned short* wswz_l3  = (unsigned short*)alloc(64512 * 2);
    unsigned short* wswz_l2  = (unsigned short*)alloc(64512 * 2);
    unsigned short* wswz_l1  = (unsigned short*)alloc(64512 * 2);
    unsigned short* wswz_cas = (unsigned short*)alloc(64512 * 2);

    // activations (NHWC bf16)
    unsigned short* offn_l3  = (unsigned short*)alloc((size_t)B * 32 * HW3 * 2);
    unsigned short* offn_l2  = (unsigned short*)alloc((size_t)B * 32 * HW2 * 2);
    unsigned short* offn_l1  = (unsigned short*)alloc((size_t)B * 32 * HW1 * 2);
    unsigned short* offn_cas = (unsigned short*)alloc((size_t)B * 32 * HW1 * 2);
    unsigned short* xn_l1    = (unsigned short*)alloc((size_t)B * 32 * HW1 * 2);
    unsigned short* L2a      = (unsigned short*)alloc((size_t)B * 32 * HW2 * 2);
    unsigned short* L2n      = (unsigned short*)alloc((size_t)B * 32 * HW2 * 2);
    unsigned short* L3a      = (unsigned short*)alloc((size_t)B * 32 * HW3 * 2);
    unsigned short* L3n      = (unsigned short*)alloc((size_t)B * 32 * HW3 * 2);
    unsigned short* L3f      = (unsigned short*)alloc((size_t)B * 32 * HW3 * 2);
    unsigned short* L2f_pre  = (unsigned short*)alloc((size_t)B * 32 * HW2 * 2);
    unsigned short* L3u      = (unsigned short*)alloc((size_t)B * 32 * HW2 * 2);
    unsigned short* L2f      = (unsigned short*)alloc((size_t)B * 32 * HW2 * 2);
    unsigned short* L1f_pre  = (unsigned short*)alloc((size_t)B * 32 * HW1 * 2);
    unsigned short* L2u      = (unsigned short*)alloc((size_t)B * 32 * HW1 * 2);
    unsigned short* L1f      = (unsigned short*)alloc((size_t)B * 32 * HW1 * 2);
    unsigned short* om       = (unsigned short*)alloc((size_t)224 * B * HW1 * 2);

    // ---- weight prep (merged) ----
    {
        Ptr4F s = {{l3_om_w, l2_om_w, l1_om_w, cas_om_w}};
        Ptr4U d = {{wswz_l3, wswz_l2, wswz_l1, wswz_cas}};
        k_swz_om4<<<dim3(CDIV(64512, 256), 4), 256, 0, stream>>>(s, d);
    }
    {
        Ptr4F s = {{w_l2c1, w_l2c2, w_l3c1, w_l3c2}};
        Ptr4U d = {{wA_l2c1, wA_l2c2, wA_l3c1, wA_l3c2}};
        k_swz_wA<32><<<dim3(CDIV(9216, 256), 4), 256, 0, stream>>>(s, d);
    }
    {
        Ptr4F s = {{w_l2fea, w_l1fea, nullptr, nullptr}};
        Ptr4U d = {{wA_l2fea, wA_l1fea, nullptr, nullptr}};
        k_swz_wA<64><<<dim3(CDIV(18432, 256), 2), 256, 0, stream>>>(s, d);
    }
    {
        Ptr4F s = {{l3_w, l2_w, l1_w, cas_w}};
        Ptr4Fd d = {{wmT_l3, wmT_l2, wmT_l1, wmT_cas}};
        k_tp_wm4<<<dim3(CDIV(9216, 256), 4), 256, 0, stream>>>(s, d);
    }

    // ---- input conversions ----
    {
        Ptr4F s = {{L1_off, offset, L1_fea, nullptr}};
        Ptr4U d = {{offn_l1, offn_cas, xn_l1, nullptr}};
        k_cvt_nhwc<<<dim3(CDIV(B * 32 * HW1, 256), 3), 256, 0, stream>>>(s, d, HW1, B);
    }
    {
        Ptr4F s = {{L2_off, nullptr, nullptr, nullptr}};
        Ptr4U d = {{offn_l2, nullptr, nullptr, nullptr}};
        k_cvt_nhwc<<<dim3(CDIV(B * 32 * HW2, 256), 1), 256, 0, stream>>>(s, d, HW2, B);
    }
    {
        Ptr4F s = {{L3_off, nullptr, nullptr, nullptr}};
        Ptr4U d = {{offn_l3, nullptr, nullptr, nullptr}};
        k_cvt_nhwc<<<dim3(CDIV(B * 32 * HW3, 256), 1), 256, 0, stream>>>(s, d, HW3, B);
    }

    // ---- feature pyramid (MFMA convs, NHWC bf16) ----
    // L2a = lrelu(conv(L1_fea, s2)); out W2=96 -> NT=3, 2 strips
    k_conv_mfma<3, 1, 2, true><<<CDIV(B * H2 * 2, 4), 256, 0, stream>>>(
        xn_l1, nullptr, wA_l2c1, b_l2c1, L2a, B, H1, W1, H2, W2);
    k_conv_mfma<3, 1, 1, true><<<CDIV(B * H2 * 2, 4), 256, 0, stream>>>(
        L2a, nullptr, wA_l2c2, b_l2c2, L2n, B, H2, W2, H2, W2);
    // L3: out W3=48 -> NT=3, 1 strip
    k_conv_mfma<3, 1, 2, true><<<CDIV(B * H3 * 1, 4), 256, 0, stream>>>(
        L2n, nullptr, wA_l3c1, b_l3c1, L3a, B, H2, W2, H3, W3);
    k_conv_mfma<3, 1, 1, true><<<CDIV(B * H3 * 1, 4), 256, 0, stream>>>(
        L3a, nullptr, wA_l3c2, b_l3c2, L3n, B, H3, W3, H3, W3);

    // ---- L3 dcn + lrelu ----
    k_gemm_om<<<CDIV(B * H3 * (W3 / 16), 4), 256, 0, stream>>>(offn_l3, wswz_l3, om, B, H3, W3);
    k_sample_conv<1><<<CDIV(B * HW3, 256), 256, 0, stream>>>(
        L3n, om, l3_om_b, wmT_l3, l3_b, nullptr, L3f, B, H3, W3);

    // ---- L2 dcn, upsample L3f, fuse ----
    k_gemm_om<<<CDIV(B * H2 * (W2 / 16), 4), 256, 0, stream>>>(offn_l2, wswz_l2, om, B, H2, W2);
    k_sample_conv<0><<<CDIV(B * HW2, 256), 256, 0, stream>>>(
        L2n, om, l2_om_b, wmT_l2, l2_b, nullptr, L2f_pre, B, H2, W2);
    k_resize2x_nhwc<<<CDIV(B * HW2 * 4, 256), 256, 0, stream>>>(L3f, L3u, B, H3, W3);
    k_conv_mfma<3, 2, 1, true><<<CDIV(B * H2 * 2, 4), 256, 0, stream>>>(
        L2f_pre, L3u, wA_l2fea, b_l2fea, L2f, B, H2, W2, H2, W2);

    // ---- L1 dcn, upsample L2f, fuse (no act) ----
    k_gemm_om<<<CDIV(B * H1 * (W1 / 16), 4), 256, 0, stream>>>(offn_l1, wswz_l1, om, B, H1, W1);
    k_sample_conv<0><<<CDIV(B * HW1, 256), 256, 0, stream>>>(
        xn_l1, om, l1_om_b, wmT_l1, l1_b, nullptr, L1f_pre, B, H1, W1);
    k_resize2x_nhwc<<<CDIV(B * HW1 * 4, 256), 256, 0, stream>>>(L2f, L2u, B, H2, W2);
    k_conv_mfma<4, 2, 1, false><<<CDIV(B * H1 * 3, 4), 256, 0, stream>>>(
        L1f_pre, L2u, wA_l1fea, b_l1fea, L1f, B, H1, W1, H1, W1);

    // ---- cascading dcn + lrelu -> output (fp32 NCHW) ----
    k_gemm_om<<<CDIV(B * H1 * (W1 / 16), 4), 256, 0, stream>>>(offn_cas, wswz_cas, om, B, H1, W1);
    k_sample_conv<2><<<CDIV(B * HW1, 256), 256, 0, stream>>>(
        L1f, om, cas_om_b, wmT_cas, cas_b, (float*)d_out, nullptr, B, H1, W1);
}

// Round 5
// 611.933 us; speedup vs baseline: 7.4810x; 1.4780x over previous
//
#include <hip/hip_runtime.h>
#include <math.h>

#define NFC 32   // feature channels
#define DGC 8    // deformable groups (Cg = 4)

#define CDIV(a, b) (((a) + (b) - 1) / (b))

typedef __attribute__((ext_vector_type(8))) short bf16x8;
typedef __attribute__((ext_vector_type(4))) float f32x4;

__device__ __forceinline__ unsigned short f2bf(float f) {
    unsigned int u = __float_as_uint(f);
    u += 0x7fffu + ((u >> 16) & 1u);          // RNE
    return (unsigned short)(u >> 16);
}
__device__ __forceinline__ float bf2f(unsigned short s) {
    return __uint_as_float((unsigned int)s << 16);
}
__device__ __forceinline__ float bf_lo(unsigned int u) { return __uint_as_float(u << 16); }
__device__ __forceinline__ float bf_hi(unsigned int u) { return __uint_as_float(u & 0xffff0000u); }

// ================= weight prep (merged via gridDim.y) =================
struct Ptr4F { const float* s[4]; };
struct Ptr4U { unsigned short* d[4]; };

// om weight (216,32,3,3) -> B-fragment swizzle (bf16):
// wswz[((t*14+nt)*64 + lane)*8 + j] = w[n=nt*16+(lane&15)][ic=(lane>>4)*8+j][t]
__global__ void k_swz_om4(Ptr4F src, Ptr4U dst) {
    const float* w = src.s[blockIdx.y];
    unsigned short* o = dst.d[blockIdx.y];
    int i = blockIdx.x * 256 + threadIdx.x;   // 9*14*64*8 = 64512
    if (i >= 9 * 14 * 64 * 8) return;
    int j  = i & 7;
    int l  = (i >> 3) & 63;
    int nt = (i >> 9) % 14;
    int t  = i / (14 * 512);
    int n  = nt * 16 + (l & 15);
    int ic = (l >> 4) * 8 + j;
    float v = (n < 216) ? w[((size_t)(n * 32 + ic)) * 9 + t] : 0.f;
    o[i] = f2bf(v);
}

// conv weight (32, ICt, 3,3) -> A-fragment swizzle (bf16), k ordered (t,ck):
// wA[(((t*KC+ck)*2+mt)*64+lane)*8+j] = w[oc=mt*16+(lane&15)][ic=ck*32+(lane>>4)*8+j][t]
template<int ICt>
__global__ void k_swz_wA(Ptr4F src, Ptr4U dst) {
    const int KC = ICt / 32;
    const float* w = src.s[blockIdx.y];
    unsigned short* o = dst.d[blockIdx.y];
    int i = blockIdx.x * 256 + threadIdx.x;   // 9*KC*2*512
    if (i >= 9 * KC * 1024) return;
    int idx = i;
    int j = idx & 7;   idx >>= 3;
    int l = idx & 63;  idx >>= 6;
    int mt = idx & 1;  idx >>= 1;
    int ck = idx % KC; idx /= KC;
    int t = idx;
    int oc = mt * 16 + (l & 15);
    int ic = ck * 32 + (l >> 4) * 8 + j;
    o[i] = f2bf(w[((size_t)(oc * ICt + ic)) * 9 + t]);
}

// main dcn weight (32,32,3,3) -> A-fragment swizzle over k = ic*9+t (matches samp rows):
// wmA[((kc*2+mt)*64 + l)*8 + j] = w[oc=mt*16+(l&15)][k=kc*32+(l>>4)*8+j], ic=k/9, t=k%9
__global__ void k_swz_wmA4(Ptr4F src, Ptr4U dst) {
    const float* w = src.s[blockIdx.y];
    unsigned short* o = dst.d[blockIdx.y];
    int i = blockIdx.x * 256 + threadIdx.x;   // 9*2*64*8 = 9216
    if (i >= 9216) return;
    int j  = i & 7;
    int l  = (i >> 3) & 63;
    int mt = (i >> 9) & 1;
    int kc = i >> 10;                          // 0..8
    int oc = mt * 16 + (l & 15);
    int k  = kc * 32 + (l >> 4) * 8 + j;
    int ic = k / 9, t = k % 9;
    o[i] = f2bf(w[((size_t)(oc * 32 + ic)) * 9 + t]);
}

// NCHW fp32 -> NHWC bf16 (merged y-layers, same HW)
__global__ void k_cvt_nhwc(Ptr4F src, Ptr4U dst, int HW, int Btot) {
    const float* in = src.s[blockIdx.y];
    unsigned short* out = dst.d[blockIdx.y];
    int i = blockIdx.x * 256 + threadIdx.x;   // over Btot*HW*32, c fastest
    if (i >= Btot * HW * 32) return;
    int c = i & 31;
    int pxf = i >> 5;
    int b = pxf / HW;
    int hw = pxf % HW;
    out[i] = f2bf(in[((size_t)(b * 32 + c)) * HW + hw]);
}

// ================= MFMA 3x3 conv, NHWC bf16 in/out =================
template<int NT, int KC, int STRIDE, bool LRELU>
__global__ __launch_bounds__(256)
void k_conv_mfma(const unsigned short* __restrict__ in1,  // NHWC bf16 32ch
                 const unsigned short* __restrict__ in2,  // NHWC bf16 32ch (KC=2) or null
                 const unsigned short* __restrict__ wA,   // A-fragment swizzled
                 const float* __restrict__ bias,          // [32]
                 unsigned short* __restrict__ out,        // NHWC bf16 32ch
                 int B, int Hin, int Win, int Hout, int Wout) {
    int wid  = (blockIdx.x * 256 + threadIdx.x) >> 6;
    int lane = threadIdx.x & 63;
    int strips = Wout / (16 * NT);
    if (wid >= B * Hout * strips) return;
    int st = wid % strips;
    int h  = (wid / strips) % Hout;
    int b  = wid / (strips * Hout);
    int px0 = st * 16 * NT;

    f32x4 acc[NT][2];
#pragma unroll
    for (int nt = 0; nt < NT; ++nt)
#pragma unroll
        for (int mt = 0; mt < 2; ++mt)
#pragma unroll
            for (int r = 0; r < 4; ++r) acc[nt][mt][r] = 0.f;

    int n  = lane & 15;
    int kq = lane >> 4;

#pragma unroll
    for (int t = 0; t < 9; ++t) {
        int hy = h * STRIDE + t / 3 - 1;
        if (hy < 0 || hy >= Hin) continue;
#pragma unroll
        for (int ck = 0; ck < KC; ++ck) {
            const unsigned short* rowp =
                ((KC == 2 && ck == 1) ? in2 : in1) + ((size_t)(b * Hin + hy) * Win) * 32;
            bf16x8 a0 = *(const bf16x8*)(wA + (size_t)((((t * KC + ck) * 2 + 0) * 64 + lane)) * 8);
            bf16x8 a1 = *(const bf16x8*)(wA + (size_t)((((t * KC + ck) * 2 + 1) * 64 + lane)) * 8);
#pragma unroll
            for (int nt = 0; nt < NT; ++nt) {
                int wx = (px0 + nt * 16 + n) * STRIDE + t % 3 - 1;
                bf16x8 bf;
#pragma unroll
                for (int j = 0; j < 8; ++j) bf[j] = 0;
                if (wx >= 0 && wx < Win)
                    bf = *(const bf16x8*)(rowp + (size_t)wx * 32 + kq * 8);
                acc[nt][0] = __builtin_amdgcn_mfma_f32_16x16x32_bf16(a0, bf, acc[nt][0], 0, 0, 0);
                acc[nt][1] = __builtin_amdgcn_mfma_f32_16x16x32_bf16(a1, bf, acc[nt][1], 0, 0, 0);
            }
        }
    }

    size_t rowbase = ((size_t)(b * Hout + h) * Wout);
#pragma unroll
    for (int mt = 0; mt < 2; ++mt) {
        float4 bs = *(const float4*)(bias + mt * 16 + kq * 4);
#pragma unroll
        for (int nt = 0; nt < NT; ++nt) {
            int px = px0 + nt * 16 + n;
            float v0 = acc[nt][mt][0] + bs.x;
            float v1 = acc[nt][mt][1] + bs.y;
            float v2 = acc[nt][mt][2] + bs.z;
            float v3 = acc[nt][mt][3] + bs.w;
            if (LRELU) {
                v0 = (v0 >= 0.f) ? v0 : 0.1f * v0;
                v1 = (v1 >= 0.f) ? v1 : 0.1f * v1;
                v2 = (v2 >= 0.f) ? v2 : 0.1f * v2;
                v3 = (v3 >= 0.f) ? v3 : 0.1f * v3;
            }
            ushort4 sv = make_ushort4(f2bf(v0), f2bf(v1), f2bf(v2), f2bf(v3));
            *(ushort4*)(out + (rowbase + px) * 32 + mt * 16 + kq * 4) = sv;
        }
    }
}

// ================= om GEMM: MFMA 16x16x32 bf16 =================
__global__ __launch_bounds__(256)
void k_gemm_om(const unsigned short* __restrict__ offn,  // (B,H,W,32) bf16
               const unsigned short* __restrict__ wswz,  // B-fragment swizzled
               unsigned short* __restrict__ om,          // [224][Npx] (216 used)
               int B, int H, int W) {
    int wid  = (blockIdx.x * 256 + threadIdx.x) >> 6;
    int lane = threadIdx.x & 63;
    int mtW = W >> 4;
    if (wid >= B * H * mtW) return;
    int mt = wid % mtW;
    int h  = (wid / mtW) % H;
    int b  = wid / (mtW * H);
    int Npx = B * H * W;
    int px0 = mt * 16;

    f32x4 acc[14];
#pragma unroll
    for (int nt = 0; nt < 14; ++nt)
#pragma unroll
        for (int r = 0; r < 4; ++r) acc[nt][r] = 0.f;

    int m  = lane & 15;
    int kq = lane >> 4;

    for (int t = 0; t < 9; ++t) {
        int hy = h + t / 3 - 1;
        if (hy < 0 || hy >= H) continue;
        int wx = px0 + m + t % 3 - 1;
        bf16x8 a;
#pragma unroll
        for (int j = 0; j < 8; ++j) a[j] = 0;
        if (wx >= 0 && wx < W)
            a = *(const bf16x8*)(offn + (((size_t)(b * H + hy) * W + wx) << 5) + kq * 8);
        const unsigned short* wp = wswz + ((size_t)t * 14 * 64 + lane) * 8;
#pragma unroll
        for (int nt = 0; nt < 14; ++nt) {
            bf16x8 bfrag = *(const bf16x8*)(wp + (size_t)nt * 64 * 8);
            acc[nt] = __builtin_amdgcn_mfma_f32_16x16x32_bf16(a, bfrag, acc[nt], 0, 0, 0);
        }
    }

    int ch_lo = lane & 15;
    int pxb = (b * H + h) * W + px0 + (lane >> 4) * 4;
#pragma unroll
    for (int nt = 0; nt < 14; ++nt) {
        int ch = nt * 16 + ch_lo;
        if (ch < 216) {
            ushort4 v = make_ushort4(f2bf(acc[nt][0]), f2bf(acc[nt][1]),
                                     f2bf(acc[nt][2]), f2bf(acc[nt][3]));
            *(ushort4*)(om + (size_t)ch * Npx + pxb) = v;
        }
    }
}

// ================= sampling (thread=(px,g)) + MFMA main conv =================
// Block = 256 thr = 32 px. Phase 1: sampling -> s_samp[px][k=ic*9+t] bf16.
// Phase 2: 4 waves, wave=(mt,nt): D[oc16][px16] via 9 MFMAs (K=288 from LDS).
// MODE 0: NHWC bf16 no act. MODE 1: NHWC bf16 + lrelu. MODE 2: NCHW fp32 + lrelu.
template<int MODE>
__global__ __launch_bounds__(256)
void k_sample_conv(const unsigned short* __restrict__ xn,  // (B,H,W,32) bf16
                   const unsigned short* __restrict__ om,  // [224][Npx]
                   const float* __restrict__ om_b,         // [216]
                   const unsigned short* __restrict__ wmA, // A-frag swizzled main w
                   const float* __restrict__ bias,         // [32]
                   float* __restrict__ outf,               // MODE 2
                   unsigned short* __restrict__ outb,      // MODE 0/1
                   int B, int H, int W) {
    const int ROW = 296;   // shorts per px row (288 + 8 pad; 592B, 16B-aligned)
    __shared__ __align__(16) unsigned short s_samp[32 * ROW];  // 18944 B

    int tid = threadIdx.x;
    int px = tid & 31, g = tid >> 5;
    int Npx = B * H * W;
    int px0 = blockIdx.x * 32;

    {   // ---- phase 1: sampling for (px, g) ----
        int idx = px0 + px;
        int w = idx % W;
        int h = (idx / W) % H;
        int b = idx / (W * H);

        float om27[27];
#pragma unroll
        for (int j = 0; j < 27; ++j)
            om27[j] = bf2f(om[(size_t)(g * 27 + j) * Npx + idx]) + om_b[g * 27 + j];

        const unsigned short* xb = xn + ((size_t)b * H * W) * 32 + g * 4;
        float Hm1 = (float)(H - 1), Wm1 = (float)(W - 1);
        unsigned short arr[36];   // [c][t], k = g*36 + c*9 + t

#pragma unroll
        for (int k = 0; k < 9; ++k) {
            float mval = 1.f / (1.f + __expf(-om27[18 + k]));
            float py  = om27[k]     + (float)(h + k / 3 - 1);
            float pxx = om27[9 + k] + (float)(w + k % 3 - 1);
            float y0f = floorf(py), x0f = floorf(pxx);
            float dy = py - y0f, dx = pxx - x0f;
            float y1f = y0f + 1.f, x1f = x0f + 1.f;
            float vy0 = (y0f >= 0.f && y0f <= Hm1) ? 1.f : 0.f;
            float vy1 = (y1f >= 0.f && y1f <= Hm1) ? 1.f : 0.f;
            float vx0 = (x0f >= 0.f && x0f <= Wm1) ? 1.f : 0.f;
            float vx1 = (x1f >= 0.f && x1f <= Wm1) ? 1.f : 0.f;
            float w00 = (1.f - dy) * (1.f - dx) * vy0 * vx0;
            float w01 = (1.f - dy) * dx * vy0 * vx1;
            float w10 = dy * (1.f - dx) * vy1 * vx0;
            float w11 = dy * dx * vy1 * vx1;
            int y0c = (int)fminf(fmaxf(y0f, 0.f), Hm1);
            int y1c = (int)fminf(fmaxf(y1f, 0.f), Hm1);
            int x0c = (int)fminf(fmaxf(x0f, 0.f), Wm1);
            int x1c = (int)fminf(fmaxf(x1f, 0.f), Wm1);

            uint2 u00 = *(const uint2*)(xb + ((size_t)y0c * W + x0c) * 32);
            uint2 u01 = *(const uint2*)(xb + ((size_t)y0c * W + x1c) * 32);
            uint2 u10 = *(const uint2*)(xb + ((size_t)y1c * W + x0c) * 32);
            uint2 u11 = *(const uint2*)(xb + ((size_t)y1c * W + x1c) * 32);

            arr[0 * 9 + k] = f2bf((w00 * bf_lo(u00.x) + w01 * bf_lo(u01.x) +
                                   w10 * bf_lo(u10.x) + w11 * bf_lo(u11.x)) * mval);
            arr[1 * 9 + k] = f2bf((w00 * bf_hi(u00.x) + w01 * bf_hi(u01.x) +
                                   w10 * bf_hi(u10.x) + w11 * bf_hi(u11.x)) * mval);
            arr[2 * 9 + k] = f2bf((w00 * bf_lo(u00.y) + w01 * bf_lo(u01.y) +
                                   w10 * bf_lo(u10.y) + w11 * bf_lo(u11.y)) * mval);
            arr[3 * 9 + k] = f2bf((w00 * bf_hi(u00.y) + w01 * bf_hi(u01.y) +
                                   w10 * bf_hi(u10.y) + w11 * bf_hi(u11.y)) * mval);
        }
        // 36 contiguous shorts at s_samp[px][g*36], 8B-aligned -> 9x ushort4
        ushort4* dst = (ushort4*)(s_samp + px * ROW + g * 36);
        const ushort4* srcp = (const ushort4*)arr;
#pragma unroll
        for (int q = 0; q < 9; ++q) dst[q] = srcp[q];
    }
    __syncthreads();

    // ---- phase 2: wave (mt, nt) computes D[oc 16][px 16] ----
    int lane = tid & 63;
    int wsid = tid >> 6;
    int mt = wsid & 1, nt = wsid >> 1;

    f32x4 acc;
#pragma unroll
    for (int r = 0; r < 4; ++r) acc[r] = 0.f;

    const unsigned short* sb = s_samp + (nt * 16 + (lane & 15)) * ROW + (lane >> 4) * 8;
#pragma unroll
    for (int kc = 0; kc < 9; ++kc) {
        bf16x8 a   = *(const bf16x8*)(wmA + ((size_t)(kc * 2 + mt) * 64 + lane) * 8);
        bf16x8 bfr = *(const bf16x8*)(sb + kc * 32);
        acc = __builtin_amdgcn_mfma_f32_16x16x32_bf16(a, bfr, acc, 0, 0, 0);
    }

    int pxg = px0 + nt * 16 + (lane & 15);
    int kq = lane >> 4;
    float4 bs = *(const float4*)(bias + mt * 16 + kq * 4);
    float v[4] = {acc[0] + bs.x, acc[1] + bs.y, acc[2] + bs.z, acc[3] + bs.w};
    if (MODE >= 1) {
#pragma unroll
        for (int r = 0; r < 4; ++r) v[r] = (v[r] >= 0.f) ? v[r] : 0.1f * v[r];
    }
    if (MODE == 2) {
        int w2 = pxg % W, h2 = (pxg / W) % H, b2 = pxg / (W * H);
#pragma unroll
        for (int r = 0; r < 4; ++r) {
            int oc = mt * 16 + kq * 4 + r;
            outf[((size_t)(b2 * 32 + oc) * H + h2) * W + w2] = v[r];
        }
    } else {
        ushort4 sv = make_ushort4(f2bf(v[0]), f2bf(v[1]), f2bf(v[2]), f2bf(v[3]));
        *(ushort4*)(outb + (size_t)pxg * 32 + mt * 16 + kq * 4) = sv;
    }
}

// ================= exact 2x bilinear upsample, NHWC bf16 =================
__global__ void k_resize2x_nhwc(const unsigned short* __restrict__ in,
                                unsigned short* __restrict__ out,
                                int B, int Hin, int Win) {
    int Hout = Hin * 2, Wout = Win * 2;
    int i = blockIdx.x * 256 + threadIdx.x;     // (b,ho,wo,q) q=ch-octet
    int total = B * Hout * Wout * 4;
    if (i >= total) return;
    int q  = i & 3;
    int wo = (i >> 2) % Wout;
    int ho = (i >> 2) / Wout % Hout;
    int b  = (i >> 2) / (Wout * Hout);
    float fy = 0.5f * (float)ho - 0.25f;
    float fx = 0.5f * (float)wo - 0.25f;
    float y0f = floorf(fy), x0f = floorf(fx);
    float wy1 = fy - y0f, wx1 = fx - x0f;
    int y0 = max(0, min((int)y0f, Hin - 1));
    int y1 = max(0, min((int)y0f + 1, Hin - 1));
    int x0 = max(0, min((int)x0f, Win - 1));
    int x1 = max(0, min((int)x0f + 1, Win - 1));
    const unsigned short* base = in + ((size_t)b * Hin * Win) * 32 + q * 8;
    const uint4 u00 = *(const uint4*)(base + ((size_t)y0 * Win + x0) * 32);
    const uint4 u01 = *(const uint4*)(base + ((size_t)y0 * Win + x1) * 32);
    const uint4 u10 = *(const uint4*)(base + ((size_t)y1 * Win + x0) * 32);
    const uint4 u11 = *(const uint4*)(base + ((size_t)y1 * Win + x1) * 32);
    float c00 = (1.f - wy1) * (1.f - wx1), c01 = (1.f - wy1) * wx1;
    float c10 = wy1 * (1.f - wx1), c11 = wy1 * wx1;
    const unsigned int* p00 = (const unsigned int*)&u00;
    const unsigned int* p01 = (const unsigned int*)&u01;
    const unsigned int* p10 = (const unsigned int*)&u10;
    const unsigned int* p11 = (const unsigned int*)&u11;
    unsigned int packed[4];
#pragma unroll
    for (int d = 0; d < 4; ++d) {
        float lo = c00 * bf_lo(p00[d]) + c01 * bf_lo(p01[d]) +
                   c10 * bf_lo(p10[d]) + c11 * bf_lo(p11[d]);
        float hi = c00 * bf_hi(p00[d]) + c01 * bf_hi(p01[d]) +
                   c10 * bf_hi(p10[d]) + c11 * bf_hi(p11[d]);
        packed[d] = (unsigned int)f2bf(lo) | ((unsigned int)f2bf(hi) << 16);
    }
    *(uint4*)(out + ((size_t)(b * Hout + ho) * Wout + wo) * 32 + q * 8) =
        make_uint4(packed[0], packed[1], packed[2], packed[3]);
}

extern "C" void kernel_launch(void* const* d_in, const int* in_sizes, int n_in,
                              void* d_out, int out_size, void* d_ws, size_t ws_size,
                              hipStream_t stream) {
    const float* L1_fea = (const float*)d_in[0];
    const float* L1_off = (const float*)d_in[1];
    const float* L2_off = (const float*)d_in[2];
    const float* L3_off = (const float*)d_in[3];
    const float* offset = (const float*)d_in[4];
    const float* w_l2c1 = (const float*)d_in[5];   const float* b_l2c1 = (const float*)d_in[6];
    const float* w_l2c2 = (const float*)d_in[7];   const float* b_l2c2 = (const float*)d_in[8];
    const float* w_l3c1 = (const float*)d_in[9];   const float* b_l3c1 = (const float*)d_in[10];
    const float* w_l3c2 = (const float*)d_in[11];  const float* b_l3c2 = (const float*)d_in[12];
    const float* w_l2fea = (const float*)d_in[13]; const float* b_l2fea = (const float*)d_in[14];
    const float* w_l1fea = (const float*)d_in[15]; const float* b_l1fea = (const float*)d_in[16];
    const float* l3_om_w = (const float*)d_in[17]; const float* l3_om_b = (const float*)d_in[18];
    const float* l3_w = (const float*)d_in[19];    const float* l3_b = (const float*)d_in[20];
    const float* l2_om_w = (const float*)d_in[21]; const float* l2_om_b = (const float*)d_in[22];
    const float* l2_w = (const float*)d_in[23];    const float* l2_b = (const float*)d_in[24];
    const float* l1_om_w = (const float*)d_in[25]; const float* l1_om_b = (const float*)d_in[26];
    const float* l1_w = (const float*)d_in[27];    const float* l1_b = (const float*)d_in[28];
    const float* cas_om_w = (const float*)d_in[29]; const float* cas_om_b = (const float*)d_in[30];
    const float* cas_w = (const float*)d_in[31];   const float* cas_b = (const float*)d_in[32];

    const int B = 4, H1 = 192, W1 = 192, H2 = 96, W2 = 96, H3 = 48, W3 = 48;
    const int HW1 = H1 * W1, HW2 = H2 * W2, HW3 = H3 * W3;

    char* ws = (char*)d_ws;
    size_t cur = 0;
    auto alloc = [&](size_t bytes) {
        char* p = ws + cur;
        cur += (bytes + 255) & ~(size_t)255;
        return p;
    };

    // weight buffers
    unsigned short* wA_l2c1  = (unsigned short*)alloc(9216 * 2);
    unsigned short* wA_l2c2  = (unsigned short*)alloc(9216 * 2);
    unsigned short* wA_l3c1  = (unsigned short*)alloc(9216 * 2);
    unsigned short* wA_l3c2  = (unsigned short*)alloc(9216 * 2);
    unsigned short* wA_l2fea = (unsigned short*)alloc(18432 * 2);
    unsigned short* wA_l1fea = (unsigned short*)alloc(18432 * 2);
    unsigned short* wmA_l3   = (unsigned short*)alloc(9216 * 2);
    unsigned short* wmA_l2   = (unsigned short*)alloc(9216 * 2);
    unsigned short* wmA_l1   = (unsigned short*)alloc(9216 * 2);
    unsigned short* wmA_cas  = (unsigned short*)alloc(9216 * 2);
    unsigned short* wswz_l3  = (unsigned short*)alloc(64512 * 2);
    unsigned short* wswz_l2  = (unsigned short*)alloc(64512 * 2);
    unsigned short* wswz_l1  = (unsigned short*)alloc(64512 * 2);
    unsigned short* wswz_cas = (unsigned short*)alloc(64512 * 2);

    // activations (NHWC bf16)
    unsigned short* offn_l3  = (unsigned short*)alloc((size_t)B * 32 * HW3 * 2);
    unsigned short* offn_l2  = (unsigned short*)alloc((size_t)B * 32 * HW2 * 2);
    unsigned short* offn_l1  = (unsigned short*)alloc((size_t)B * 32 * HW1 * 2);
    unsigned short* offn_cas = (unsigned short*)alloc((size_t)B * 32 * HW1 * 2);
    unsigned short* xn_l1    = (unsigned short*)alloc((size_t)B * 32 * HW1 * 2);
    unsigned short* L2a      = (unsigned short*)alloc((size_t)B * 32 * HW2 * 2);
    unsigned short* L2n      = (unsigned short*)alloc((size_t)B * 32 * HW2 * 2);
    unsigned short* L3a      = (unsigned short*)alloc((size_t)B * 32 * HW3 * 2);
    unsigned short* L3n      = (unsigned short*)alloc((size_t)B * 32 * HW3 * 2);
    unsigned short* L3f      = (unsigned short*)alloc((size_t)B * 32 * HW3 * 2);
    unsigned short* L2f_pre  = (unsigned short*)alloc((size_t)B * 32 * HW2 * 2);
    unsigned short* L3u      = (unsigned short*)alloc((size_t)B * 32 * HW2 * 2);
    unsigned short* L2f      = (unsigned short*)alloc((size_t)B * 32 * HW2 * 2);
    unsigned short* L1f_pre  = (unsigned short*)alloc((size_t)B * 32 * HW1 * 2);
    unsigned short* L2u      = (unsigned short*)alloc((size_t)B * 32 * HW1 * 2);
    unsigned short* L1f      = (unsigned short*)alloc((size_t)B * 32 * HW1 * 2);
    unsigned short* om       = (unsigned short*)alloc((size_t)224 * B * HW1 * 2);

    // ---- weight prep (merged) ----
    {
        Ptr4F s = {{l3_om_w, l2_om_w, l1_om_w, cas_om_w}};
        Ptr4U d = {{wswz_l3, wswz_l2, wswz_l1, wswz_cas}};
        k_swz_om4<<<dim3(CDIV(64512, 256), 4), 256, 0, stream>>>(s, d);
    }
    {
        Ptr4F s = {{w_l2c1, w_l2c2, w_l3c1, w_l3c2}};
        Ptr4U d = {{wA_l2c1, wA_l2c2, wA_l3c1, wA_l3c2}};
        k_swz_wA<32><<<dim3(CDIV(9216, 256), 4), 256, 0, stream>>>(s, d);
    }
    {
        Ptr4F s = {{w_l2fea, w_l1fea, nullptr, nullptr}};
        Ptr4U d = {{wA_l2fea, wA_l1fea, nullptr, nullptr}};
        k_swz_wA<64><<<dim3(CDIV(18432, 256), 2), 256, 0, stream>>>(s, d);
    }
    {
        Ptr4F s = {{l3_w, l2_w, l1_w, cas_w}};
        Ptr4U d = {{wmA_l3, wmA_l2, wmA_l1, wmA_cas}};
        k_swz_wmA4<<<dim3(CDIV(9216, 256), 4), 256, 0, stream>>>(s, d);
    }

    // ---- input conversions ----
    {
        Ptr4F s = {{L1_off, offset, L1_fea, nullptr}};
        Ptr4U d = {{offn_l1, offn_cas, xn_l1, nullptr}};
        k_cvt_nhwc<<<dim3(CDIV(B * 32 * HW1, 256), 3), 256, 0, stream>>>(s, d, HW1, B);
    }
    {
        Ptr4F s = {{L2_off, nullptr, nullptr, nullptr}};
        Ptr4U d = {{offn_l2, nullptr, nullptr, nullptr}};
        k_cvt_nhwc<<<dim3(CDIV(B * 32 * HW2, 256), 1), 256, 0, stream>>>(s, d, HW2, B);
    }
    {
        Ptr4F s = {{L3_off, nullptr, nullptr, nullptr}};
        Ptr4U d = {{offn_l3, nullptr, nullptr, nullptr}};
        k_cvt_nhwc<<<dim3(CDIV(B * 32 * HW3, 256), 1), 256, 0, stream>>>(s, d, HW3, B);
    }

    // ---- feature pyramid (MFMA convs, NHWC bf16) ----
    k_conv_mfma<3, 1, 2, true><<<CDIV(B * H2 * 2, 4), 256, 0, stream>>>(
        xn_l1, nullptr, wA_l2c1, b_l2c1, L2a, B, H1, W1, H2, W2);
    k_conv_mfma<3, 1, 1, true><<<CDIV(B * H2 * 2, 4), 256, 0, stream>>>(
        L2a, nullptr, wA_l2c2, b_l2c2, L2n, B, H2, W2, H2, W2);
    k_conv_mfma<3, 1, 2, true><<<CDIV(B * H3 * 1, 4), 256, 0, stream>>>(
        L2n, nullptr, wA_l3c1, b_l3c1, L3a, B, H2, W2, H3, W3);
    k_conv_mfma<3, 1, 1, true><<<CDIV(B * H3 * 1, 4), 256, 0, stream>>>(
        L3a, nullptr, wA_l3c2, b_l3c2, L3n, B, H3, W3, H3, W3);

    // ---- L3 dcn + lrelu ----
    k_gemm_om<<<CDIV(B * H3 * (W3 / 16), 4), 256, 0, stream>>>(offn_l3, wswz_l3, om, B, H3, W3);
    k_sample_conv<1><<<B * HW3 / 32, 256, 0, stream>>>(
        L3n, om, l3_om_b, wmA_l3, l3_b, nullptr, L3f, B, H3, W3);

    // ---- L2 dcn, upsample L3f, fuse ----
    k_gemm_om<<<CDIV(B * H2 * (W2 / 16), 4), 256, 0, stream>>>(offn_l2, wswz_l2, om, B, H2, W2);
    k_sample_conv<0><<<B * HW2 / 32, 256, 0, stream>>>(
        L2n, om, l2_om_b, wmA_l2, l2_b, nullptr, L2f_pre, B, H2, W2);
    k_resize2x_nhwc<<<CDIV(B * HW2 * 4, 256), 256, 0, stream>>>(L3f, L3u, B, H3, W3);
    k_conv_mfma<3, 2, 1, true><<<CDIV(B * H2 * 2, 4), 256, 0, stream>>>(
        L2f_pre, L3u, wA_l2fea, b_l2fea, L2f, B, H2, W2, H2, W2);

    // ---- L1 dcn, upsample L2f, fuse (no act) ----
    k_gemm_om<<<CDIV(B * H1 * (W1 / 16), 4), 256, 0, stream>>>(offn_l1, wswz_l1, om, B, H1, W1);
    k_sample_conv<0><<<B * HW1 / 32, 256, 0, stream>>>(
        xn_l1, om, l1_om_b, wmA_l1, l1_b, nullptr, L1f_pre, B, H1, W1);
    k_resize2x_nhwc<<<CDIV(B * HW1 * 4, 256), 256, 0, stream>>>(L2f, L2u, B, H2, W2);
    k_conv_mfma<4, 2, 1, false><<<CDIV(B * H1 * 3, 4), 256, 0, stream>>>(
        L1f_pre, L2u, wA_l1fea, b_l1fea, L1f, B, H1, W1, H1, W1);

    // ---- cascading dcn + lrelu -> output (fp32 NCHW) ----
    k_gemm_om<<<CDIV(B * H1 * (W1 / 16), 4), 256, 0, stream>>>(offn_cas, wswz_cas, om, B, H1, W1);
    k_sample_conv<2><<<B * HW1 / 32, 256, 0, stream>>>(
        L1f, om, cas_om_b, wmA_cas, cas_b, (float*)d_out, nullptr, B, H1, W1);
}

// Round 6
// 606.817 us; speedup vs baseline: 7.5441x; 1.0084x over previous
//
#include <hip/hip_runtime.h>
#include <math.h>

#define NFC 32   // feature channels
#define DGC 8    // deformable groups (Cg = 4)

#define CDIV(a, b) (((a) + (b) - 1) / (b))

typedef __attribute__((ext_vector_type(8))) short bf16x8;
typedef __attribute__((ext_vector_type(4))) float f32x4;

__device__ __forceinline__ unsigned short f2bf(float f) {
    unsigned int u = __float_as_uint(f);
    u += 0x7fffu + ((u >> 16) & 1u);          // RNE
    return (unsigned short)(u >> 16);
}
__device__ __forceinline__ float bf2f(unsigned short s) {
    return __uint_as_float((unsigned int)s << 16);
}
__device__ __forceinline__ float bf_lo(unsigned int u) { return __uint_as_float(u << 16); }
__device__ __forceinline__ float bf_hi(unsigned int u) { return __uint_as_float(u & 0xffff0000u); }

// ================= weight prep (merged via gridDim.y) =================
struct Ptr4F { const float* s[4]; };
struct Ptr4U { unsigned short* d[4]; };

// om weight (216,32,3,3) -> B-fragment swizzle (bf16):
// wswz[((t*14+nt)*64 + lane)*8 + j] = w[n=nt*16+(lane&15)][ic=(lane>>4)*8+j][t]
__global__ void k_swz_om4(Ptr4F src, Ptr4U dst) {
    const float* w = src.s[blockIdx.y];
    unsigned short* o = dst.d[blockIdx.y];
    int i = blockIdx.x * 256 + threadIdx.x;   // 9*14*64*8 = 64512
    if (i >= 9 * 14 * 64 * 8) return;
    int j  = i & 7;
    int l  = (i >> 3) & 63;
    int nt = (i >> 9) % 14;
    int t  = i / (14 * 512);
    int n  = nt * 16 + (l & 15);
    int ic = (l >> 4) * 8 + j;
    float v = (n < 216) ? w[((size_t)(n * 32 + ic)) * 9 + t] : 0.f;
    o[i] = f2bf(v);
}

// conv weight (32, ICt, 3,3) -> A-fragment swizzle (bf16), k ordered (t,ck):
// wA[(((t*KC+ck)*2+mt)*64+lane)*8+j] = w[oc=mt*16+(lane&15)][ic=ck*32+(lane>>4)*8+j][t]
template<int ICt>
__global__ void k_swz_wA(Ptr4F src, Ptr4U dst) {
    const int KC = ICt / 32;
    const float* w = src.s[blockIdx.y];
    unsigned short* o = dst.d[blockIdx.y];
    int i = blockIdx.x * 256 + threadIdx.x;   // 9*KC*2*512
    if (i >= 9 * KC * 1024) return;
    int idx = i;
    int j = idx & 7;   idx >>= 3;
    int l = idx & 63;  idx >>= 6;
    int mt = idx & 1;  idx >>= 1;
    int ck = idx % KC; idx /= KC;
    int t = idx;
    int oc = mt * 16 + (l & 15);
    int ic = ck * 32 + (l >> 4) * 8 + j;
    o[i] = f2bf(w[((size_t)(oc * ICt + ic)) * 9 + t]);
}

// main dcn weight (32,32,3,3) -> A-fragment swizzle over k = ic*9+t (matches samp rows):
// wmA[((kc*2+mt)*64 + l)*8 + j] = w[oc=mt*16+(l&15)][k=kc*32+(l>>4)*8+j], ic=k/9, t=k%9
__global__ void k_swz_wmA4(Ptr4F src, Ptr4U dst) {
    const float* w = src.s[blockIdx.y];
    unsigned short* o = dst.d[blockIdx.y];
    int i = blockIdx.x * 256 + threadIdx.x;   // 9*2*64*8 = 9216
    if (i >= 9216) return;
    int j  = i & 7;
    int l  = (i >> 3) & 63;
    int mt = (i >> 9) & 1;
    int kc = i >> 10;                          // 0..8
    int oc = mt * 16 + (l & 15);
    int k  = kc * 32 + (l >> 4) * 8 + j;
    int ic = k / 9, t = k % 9;
    o[i] = f2bf(w[((size_t)(oc * 32 + ic)) * 9 + t]);
}

// NCHW fp32 -> NHWC bf16 (merged y-layers, same HW)
__global__ void k_cvt_nhwc(Ptr4F src, Ptr4U dst, int HW, int Btot) {
    const float* in = src.s[blockIdx.y];
    unsigned short* out = dst.d[blockIdx.y];
    int i = blockIdx.x * 256 + threadIdx.x;   // over Btot*HW*32, c fastest
    if (i >= Btot * HW * 32) return;
    int c = i & 31;
    int pxf = i >> 5;
    int b = pxf / HW;
    int hw = pxf % HW;
    out[i] = f2bf(in[((size_t)(b * 32 + c)) * HW + hw]);
}

// ================= MFMA 3x3 conv, NHWC bf16 in/out =================
template<int NT, int KC, int STRIDE, bool LRELU>
__global__ __launch_bounds__(256)
void k_conv_mfma(const unsigned short* __restrict__ in1,  // NHWC bf16 32ch
                 const unsigned short* __restrict__ in2,  // NHWC bf16 32ch (KC=2) or null
                 const unsigned short* __restrict__ wA,   // A-fragment swizzled
                 const float* __restrict__ bias,          // [32]
                 unsigned short* __restrict__ out,        // NHWC bf16 32ch
                 int B, int Hin, int Win, int Hout, int Wout) {
    int wid  = (blockIdx.x * 256 + threadIdx.x) >> 6;
    int lane = threadIdx.x & 63;
    int strips = Wout / (16 * NT);
    if (wid >= B * Hout * strips) return;
    int st = wid % strips;
    int h  = (wid / strips) % Hout;
    int b  = wid / (strips * Hout);
    int px0 = st * 16 * NT;

    f32x4 acc[NT][2];
#pragma unroll
    for (int nt = 0; nt < NT; ++nt)
#pragma unroll
        for (int mt = 0; mt < 2; ++mt)
#pragma unroll
            for (int r = 0; r < 4; ++r) acc[nt][mt][r] = 0.f;

    int n  = lane & 15;
    int kq = lane >> 4;

#pragma unroll
    for (int t = 0; t < 9; ++t) {
        int hy = h * STRIDE + t / 3 - 1;
        if (hy < 0 || hy >= Hin) continue;
#pragma unroll
        for (int ck = 0; ck < KC; ++ck) {
            const unsigned short* rowp =
                ((KC == 2 && ck == 1) ? in2 : in1) + ((size_t)(b * Hin + hy) * Win) * 32;
            bf16x8 a0 = *(const bf16x8*)(wA + (size_t)((((t * KC + ck) * 2 + 0) * 64 + lane)) * 8);
            bf16x8 a1 = *(const bf16x8*)(wA + (size_t)((((t * KC + ck) * 2 + 1) * 64 + lane)) * 8);
#pragma unroll
            for (int nt = 0; nt < NT; ++nt) {
                int wx = (px0 + nt * 16 + n) * STRIDE + t % 3 - 1;
                bf16x8 bf;
#pragma unroll
                for (int j = 0; j < 8; ++j) bf[j] = 0;
                if (wx >= 0 && wx < Win)
                    bf = *(const bf16x8*)(rowp + (size_t)wx * 32 + kq * 8);
                acc[nt][0] = __builtin_amdgcn_mfma_f32_16x16x32_bf16(a0, bf, acc[nt][0], 0, 0, 0);
                acc[nt][1] = __builtin_amdgcn_mfma_f32_16x16x32_bf16(a1, bf, acc[nt][1], 0, 0, 0);
            }
        }
    }

    size_t rowbase = ((size_t)(b * Hout + h) * Wout);
#pragma unroll
    for (int mt = 0; mt < 2; ++mt) {
        float4 bs = *(const float4*)(bias + mt * 16 + kq * 4);
#pragma unroll
        for (int nt = 0; nt < NT; ++nt) {
            int px = px0 + nt * 16 + n;
            float v0 = acc[nt][mt][0] + bs.x;
            float v1 = acc[nt][mt][1] + bs.y;
            float v2 = acc[nt][mt][2] + bs.z;
            float v3 = acc[nt][mt][3] + bs.w;
            if (LRELU) {
                v0 = (v0 >= 0.f) ? v0 : 0.1f * v0;
                v1 = (v1 >= 0.f) ? v1 : 0.1f * v1;
                v2 = (v2 >= 0.f) ? v2 : 0.1f * v2;
                v3 = (v3 >= 0.f) ? v3 : 0.1f * v3;
            }
            ushort4 sv = make_ushort4(f2bf(v0), f2bf(v1), f2bf(v2), f2bf(v3));
            *(ushort4*)(out + (rowbase + px) * 32 + mt * 16 + kq * 4) = sv;
        }
    }
}

// ========== fully fused DCN: om GEMM (LDS) + sampling + MFMA main conv ==========
// Block = 256 thr = 32 px.
// Phase 0: om GEMM for 32 px -> s_om[216][36] bf16. Wave wv handles nt = wv*4..wv*4+3
//          (nt>=14 skipped), both 16-px m-tiles.
// Phase 1: thread=(px,g) sampling -> s_samp[px][k=ic*9+t] bf16.
// Phase 2: wave=(mt,nt): D[oc16][px16] via 9 MFMAs (K=288 from LDS).
// MODE 0: NHWC bf16 no act. MODE 1: NHWC bf16 + lrelu. MODE 2: NCHW fp32 + lrelu.
template<int MODE>
__global__ __launch_bounds__(256)
void k_dcn_fused(const unsigned short* __restrict__ offn, // (B,H,W,32) bf16
                 const unsigned short* __restrict__ wswz, // om w B-frag swizzled
                 const float* __restrict__ om_b,          // [216]
                 const unsigned short* __restrict__ xn,   // (B,H,W,32) bf16
                 const unsigned short* __restrict__ wmA,  // main w A-frag swizzled
                 const float* __restrict__ bias,          // [32]
                 float* __restrict__ outf,                // MODE 2
                 unsigned short* __restrict__ outb,       // MODE 0/1
                 int B, int H, int W) {
    const int ROW = 296;   // s_samp row stride (288 + 8 pad)
    const int OMR = 36;    // s_om row stride (32 px + 4 pad; 72B, 8B-aligned rows)
    __shared__ __align__(16) unsigned short s_om[216 * OMR];   // 15552 B
    __shared__ __align__(16) unsigned short s_samp[32 * ROW];  // 18944 B

    int tid = threadIdx.x;
    int lane = tid & 63;
    int wv = tid >> 6;
    int px0 = blockIdx.x * 32;

    // ---- phase 0: om GEMM into s_om ----
    {
        int n  = lane & 15;     // A: pixel-in-tile; C: channel-in-tile
        int kq = lane >> 4;

        // per m-tile geometry (16 px within one row; W % 16 == 0)
        int bmt[2], hmt[2], wmt[2];
#pragma unroll
        for (int mt = 0; mt < 2; ++mt) {
            int p0 = px0 + mt * 16;
            bmt[mt] = p0 / (H * W);
            hmt[mt] = (p0 / W) % H;
            wmt[mt] = p0 % W;
        }

        f32x4 acc[4][2];
#pragma unroll
        for (int i = 0; i < 4; ++i)
#pragma unroll
            for (int mt = 0; mt < 2; ++mt)
#pragma unroll
                for (int r = 0; r < 4; ++r) acc[i][mt][r] = 0.f;

#pragma unroll
        for (int t = 0; t < 9; ++t) {
            bf16x8 a[2];
#pragma unroll
            for (int mt = 0; mt < 2; ++mt) {
#pragma unroll
                for (int j = 0; j < 8; ++j) a[mt][j] = 0;
                int hy = hmt[mt] + t / 3 - 1;
                int wx = wmt[mt] + n + t % 3 - 1;
                if (hy >= 0 && hy < H && wx >= 0 && wx < W)
                    a[mt] = *(const bf16x8*)(offn +
                        (((size_t)(bmt[mt] * H + hy) * W + wx) << 5) + kq * 8);
            }
#pragma unroll
            for (int i = 0; i < 4; ++i) {
                int nt = wv * 4 + i;
                if (nt < 14) {
                    bf16x8 bf = *(const bf16x8*)(wswz + (((size_t)t * 14 + nt) * 64 + lane) * 8);
                    acc[i][0] = __builtin_amdgcn_mfma_f32_16x16x32_bf16(a[0], bf, acc[i][0], 0, 0, 0);
                    acc[i][1] = __builtin_amdgcn_mfma_f32_16x16x32_bf16(a[1], bf, acc[i][1], 0, 0, 0);
                }
            }
        }

        // C store: ch = nt*16 + n (col), px_local = mt*16 + kq*4 + r (row)
#pragma unroll
        for (int i = 0; i < 4; ++i) {
            int nt = wv * 4 + i;
            if (nt < 14) {
                int ch = nt * 16 + n;
                if (ch < 216) {
#pragma unroll
                    for (int mt = 0; mt < 2; ++mt) {
                        ushort4 v = make_ushort4(f2bf(acc[i][mt][0]), f2bf(acc[i][mt][1]),
                                                 f2bf(acc[i][mt][2]), f2bf(acc[i][mt][3]));
                        *(ushort4*)(s_om + ch * OMR + mt * 16 + kq * 4) = v;
                    }
                }
            }
        }
    }
    __syncthreads();

    // ---- phase 1: sampling for (px, g) ----
    {
        int px = tid & 31, g = tid >> 5;
        int idx = px0 + px;
        int w = idx % W;
        int h = (idx / W) % H;
        int b = idx / (W * H);

        float om27[27];
#pragma unroll
        for (int j = 0; j < 27; ++j)
            om27[j] = bf2f(s_om[(g * 27 + j) * OMR + px]) + om_b[g * 27 + j];

        const unsigned short* xb = xn + ((size_t)b * H * W) * 32 + g * 4;
        float Hm1 = (float)(H - 1), Wm1 = (float)(W - 1);
        unsigned short arr[36];   // [c][t], k = g*36 + c*9 + t

#pragma unroll
        for (int k = 0; k < 9; ++k) {
            float mval = 1.f / (1.f + __expf(-om27[18 + k]));
            float py  = om27[k]     + (float)(h + k / 3 - 1);
            float pxx = om27[9 + k] + (float)(w + k % 3 - 1);
            float y0f = floorf(py), x0f = floorf(pxx);
            float dy = py - y0f, dx = pxx - x0f;
            float y1f = y0f + 1.f, x1f = x0f + 1.f;
            float vy0 = (y0f >= 0.f && y0f <= Hm1) ? 1.f : 0.f;
            float vy1 = (y1f >= 0.f && y1f <= Hm1) ? 1.f : 0.f;
            float vx0 = (x0f >= 0.f && x0f <= Wm1) ? 1.f : 0.f;
            float vx1 = (x1f >= 0.f && x1f <= Wm1) ? 1.f : 0.f;
            float w00 = (1.f - dy) * (1.f - dx) * vy0 * vx0;
            float w01 = (1.f - dy) * dx * vy0 * vx1;
            float w10 = dy * (1.f - dx) * vy1 * vx0;
            float w11 = dy * dx * vy1 * vx1;
            int y0c = (int)fminf(fmaxf(y0f, 0.f), Hm1);
            int y1c = (int)fminf(fmaxf(y1f, 0.f), Hm1);
            int x0c = (int)fminf(fmaxf(x0f, 0.f), Wm1);
            int x1c = (int)fminf(fmaxf(x1f, 0.f), Wm1);

            uint2 u00 = *(const uint2*)(xb + ((size_t)y0c * W + x0c) * 32);
            uint2 u01 = *(const uint2*)(xb + ((size_t)y0c * W + x1c) * 32);
            uint2 u10 = *(const uint2*)(xb + ((size_t)y1c * W + x0c) * 32);
            uint2 u11 = *(const uint2*)(xb + ((size_t)y1c * W + x1c) * 32);

            arr[0 * 9 + k] = f2bf((w00 * bf_lo(u00.x) + w01 * bf_lo(u01.x) +
                                   w10 * bf_lo(u10.x) + w11 * bf_lo(u11.x)) * mval);
            arr[1 * 9 + k] = f2bf((w00 * bf_hi(u00.x) + w01 * bf_hi(u01.x) +
                                   w10 * bf_hi(u10.x) + w11 * bf_hi(u11.x)) * mval);
            arr[2 * 9 + k] = f2bf((w00 * bf_lo(u00.y) + w01 * bf_lo(u01.y) +
                                   w10 * bf_lo(u10.y) + w11 * bf_lo(u11.y)) * mval);
            arr[3 * 9 + k] = f2bf((w00 * bf_hi(u00.y) + w01 * bf_hi(u01.y) +
                                   w10 * bf_hi(u10.y) + w11 * bf_hi(u11.y)) * mval);
        }
        ushort4* dst = (ushort4*)(s_samp + px * ROW + g * 36);
        const ushort4* srcp = (const ushort4*)arr;
#pragma unroll
        for (int q = 0; q < 9; ++q) dst[q] = srcp[q];
    }
    __syncthreads();

    // ---- phase 2: wave (mt, nt) computes D[oc 16][px 16] ----
    int wsid = tid >> 6;
    int mt = wsid & 1, nt2 = wsid >> 1;

    f32x4 acc;
#pragma unroll
    for (int r = 0; r < 4; ++r) acc[r] = 0.f;

    const unsigned short* sb = s_samp + (nt2 * 16 + (lane & 15)) * ROW + (lane >> 4) * 8;
#pragma unroll
    for (int kc = 0; kc < 9; ++kc) {
        bf16x8 a   = *(const bf16x8*)(wmA + ((size_t)(kc * 2 + mt) * 64 + lane) * 8);
        bf16x8 bfr = *(const bf16x8*)(sb + kc * 32);
        acc = __builtin_amdgcn_mfma_f32_16x16x32_bf16(a, bfr, acc, 0, 0, 0);
    }

    int pxg = px0 + nt2 * 16 + (lane & 15);
    int kq = lane >> 4;
    float4 bs = *(const float4*)(bias + mt * 16 + kq * 4);
    float v[4] = {acc[0] + bs.x, acc[1] + bs.y, acc[2] + bs.z, acc[3] + bs.w};
    if (MODE >= 1) {
#pragma unroll
        for (int r = 0; r < 4; ++r) v[r] = (v[r] >= 0.f) ? v[r] : 0.1f * v[r];
    }
    if (MODE == 2) {
        int w2 = pxg % W, h2 = (pxg / W) % H, b2 = pxg / (W * H);
#pragma unroll
        for (int r = 0; r < 4; ++r) {
            int oc = mt * 16 + kq * 4 + r;
            outf[((size_t)(b2 * 32 + oc) * H + h2) * W + w2] = v[r];
        }
    } else {
        ushort4 sv = make_ushort4(f2bf(v[0]), f2bf(v[1]), f2bf(v[2]), f2bf(v[3]));
        *(ushort4*)(outb + (size_t)pxg * 32 + mt * 16 + kq * 4) = sv;
    }
}

// ================= exact 2x bilinear upsample, NHWC bf16 =================
__global__ void k_resize2x_nhwc(const unsigned short* __restrict__ in,
                                unsigned short* __restrict__ out,
                                int B, int Hin, int Win) {
    int Hout = Hin * 2, Wout = Win * 2;
    int i = blockIdx.x * 256 + threadIdx.x;     // (b,ho,wo,q) q=ch-octet
    int total = B * Hout * Wout * 4;
    if (i >= total) return;
    int q  = i & 3;
    int wo = (i >> 2) % Wout;
    int ho = (i >> 2) / Wout % Hout;
    int b  = (i >> 2) / (Wout * Hout);
    float fy = 0.5f * (float)ho - 0.25f;
    float fx = 0.5f * (float)wo - 0.25f;
    float y0f = floorf(fy), x0f = floorf(fx);
    float wy1 = fy - y0f, wx1 = fx - x0f;
    int y0 = max(0, min((int)y0f, Hin - 1));
    int y1 = max(0, min((int)y0f + 1, Hin - 1));
    int x0 = max(0, min((int)x0f, Win - 1));
    int x1 = max(0, min((int)x0f + 1, Win - 1));
    const unsigned short* base = in + ((size_t)b * Hin * Win) * 32 + q * 8;
    const uint4 u00 = *(const uint4*)(base + ((size_t)y0 * Win + x0) * 32);
    const uint4 u01 = *(const uint4*)(base + ((size_t)y0 * Win + x1) * 32);
    const uint4 u10 = *(const uint4*)(base + ((size_t)y1 * Win + x0) * 32);
    const uint4 u11 = *(const uint4*)(base + ((size_t)y1 * Win + x1) * 32);
    float c00 = (1.f - wy1) * (1.f - wx1), c01 = (1.f - wy1) * wx1;
    float c10 = wy1 * (1.f - wx1), c11 = wy1 * wx1;
    const unsigned int* p00 = (const unsigned int*)&u00;
    const unsigned int* p01 = (const unsigned int*)&u01;
    const unsigned int* p10 = (const unsigned int*)&u10;
    const unsigned int* p11 = (const unsigned int*)&u11;
    unsigned int packed[4];
#pragma unroll
    for (int d = 0; d < 4; ++d) {
        float lo = c00 * bf_lo(p00[d]) + c01 * bf_lo(p01[d]) +
                   c10 * bf_lo(p10[d]) + c11 * bf_lo(p11[d]);
        float hi = c00 * bf_hi(p00[d]) + c01 * bf_hi(p01[d]) +
                   c10 * bf_hi(p10[d]) + c11 * bf_hi(p11[d]);
        packed[d] = (unsigned int)f2bf(lo) | ((unsigned int)f2bf(hi) << 16);
    }
    *(uint4*)(out + ((size_t)(b * Hout + ho) * Wout + wo) * 32 + q * 8) =
        make_uint4(packed[0], packed[1], packed[2], packed[3]);
}

extern "C" void kernel_launch(void* const* d_in, const int* in_sizes, int n_in,
                              void* d_out, int out_size, void* d_ws, size_t ws_size,
                              hipStream_t stream) {
    const float* L1_fea = (const float*)d_in[0];
    const float* L1_off = (const float*)d_in[1];
    const float* L2_off = (const float*)d_in[2];
    const float* L3_off = (const float*)d_in[3];
    const float* offset = (const float*)d_in[4];
    const float* w_l2c1 = (const float*)d_in[5];   const float* b_l2c1 = (const float*)d_in[6];
    const float* w_l2c2 = (const float*)d_in[7];   const float* b_l2c2 = (const float*)d_in[8];
    const float* w_l3c1 = (const float*)d_in[9];   const float* b_l3c1 = (const float*)d_in[10];
    const float* w_l3c2 = (const float*)d_in[11];  const float* b_l3c2 = (const float*)d_in[12];
    const float* w_l2fea = (const float*)d_in[13]; const float* b_l2fea = (const float*)d_in[14];
    const float* w_l1fea = (const float*)d_in[15]; const float* b_l1fea = (const float*)d_in[16];
    const float* l3_om_w = (const float*)d_in[17]; const float* l3_om_b = (const float*)d_in[18];
    const float* l3_w = (const float*)d_in[19];    const float* l3_b = (const float*)d_in[20];
    const float* l2_om_w = (const float*)d_in[21]; const float* l2_om_b = (const float*)d_in[22];
    const float* l2_w = (const float*)d_in[23];    const float* l2_b = (const float*)d_in[24];
    const float* l1_om_w = (const float*)d_in[25]; const float* l1_om_b = (const float*)d_in[26];
    const float* l1_w = (const float*)d_in[27];    const float* l1_b = (const float*)d_in[28];
    const float* cas_om_w = (const float*)d_in[29]; const float* cas_om_b = (const float*)d_in[30];
    const float* cas_w = (const float*)d_in[31];   const float* cas_b = (const float*)d_in[32];

    const int B = 4, H1 = 192, W1 = 192, H2 = 96, W2 = 96, H3 = 48, W3 = 48;
    const int HW1 = H1 * W1, HW2 = H2 * W2, HW3 = H3 * W3;

    char* ws = (char*)d_ws;
    size_t cur = 0;
    auto alloc = [&](size_t bytes) {
        char* p = ws + cur;
        cur += (bytes + 255) & ~(size_t)255;
        return p;
    };

    // weight buffers
    unsigned short* wA_l2c1  = (unsigned short*)alloc(9216 * 2);
    unsigned short* wA_l2c2  = (unsigned short*)alloc(9216 * 2);
    unsigned short* wA_l3c1  = (unsigned short*)alloc(9216 * 2);
    unsigned short* wA_l3c2  = (unsigned short*)alloc(9216 * 2);
    unsigned short* wA_l2fea = (unsigned short*)alloc(18432 * 2);
    unsigned short* wA_l1fea = (unsigned short*)alloc(18432 * 2);
    unsigned short* wmA_l3   = (unsigned short*)alloc(9216 * 2);
    unsigned short* wmA_l2   = (unsigned short*)alloc(9216 * 2);
    unsigned short* wmA_l1   = (unsigned short*)alloc(9216 * 2);
    unsigned short* wmA_cas  = (unsigned short*)alloc(9216 * 2);
    unsigned short* wswz_l3  = (unsigned short*)alloc(64512 * 2);
    unsigned short* wswz_l2  = (unsigned short*)alloc(64512 * 2);
    unsigned short* wswz_l1  = (unsigned short*)alloc(64512 * 2);
    unsigned short* wswz_cas = (unsigned short*)alloc(64512 * 2);

    // activations (NHWC bf16)
    unsigned short* offn_l3  = (unsigned short*)alloc((size_t)B * 32 * HW3 * 2);
    unsigned short* offn_l2  = (unsigned short*)alloc((size_t)B * 32 * HW2 * 2);
    unsigned short* offn_l1  = (unsigned short*)alloc((size_t)B * 32 * HW1 * 2);
    unsigned short* offn_cas = (unsigned short*)alloc((size_t)B * 32 * HW1 * 2);
    unsigned short* xn_l1    = (unsigned short*)alloc((size_t)B * 32 * HW1 * 2);
    unsigned short* L2a      = (unsigned short*)alloc((size_t)B * 32 * HW2 * 2);
    unsigned short* L2n      = (unsigned short*)alloc((size_t)B * 32 * HW2 * 2);
    unsigned short* L3a      = (unsigned short*)alloc((size_t)B * 32 * HW3 * 2);
    unsigned short* L3n      = (unsigned short*)alloc((size_t)B * 32 * HW3 * 2);
    unsigned short* L3f      = (unsigned short*)alloc((size_t)B * 32 * HW3 * 2);
    unsigned short* L2f_pre  = (unsigned short*)alloc((size_t)B * 32 * HW2 * 2);
    unsigned short* L3u      = (unsigned short*)alloc((size_t)B * 32 * HW2 * 2);
    unsigned short* L2f      = (unsigned short*)alloc((size_t)B * 32 * HW2 * 2);
    unsigned short* L1f_pre  = (unsigned short*)alloc((size_t)B * 32 * HW1 * 2);
    unsigned short* L2u      = (unsigned short*)alloc((size_t)B * 32 * HW1 * 2);
    unsigned short* L1f      = (unsigned short*)alloc((size_t)B * 32 * HW1 * 2);

    // ---- weight prep (merged) ----
    {
        Ptr4F s = {{l3_om_w, l2_om_w, l1_om_w, cas_om_w}};
        Ptr4U d = {{wswz_l3, wswz_l2, wswz_l1, wswz_cas}};
        k_swz_om4<<<dim3(CDIV(64512, 256), 4), 256, 0, stream>>>(s, d);
    }
    {
        Ptr4F s = {{w_l2c1, w_l2c2, w_l3c1, w_l3c2}};
        Ptr4U d = {{wA_l2c1, wA_l2c2, wA_l3c1, wA_l3c2}};
        k_swz_wA<32><<<dim3(CDIV(9216, 256), 4), 256, 0, stream>>>(s, d);
    }
    {
        Ptr4F s = {{w_l2fea, w_l1fea, nullptr, nullptr}};
        Ptr4U d = {{wA_l2fea, wA_l1fea, nullptr, nullptr}};
        k_swz_wA<64><<<dim3(CDIV(18432, 256), 2), 256, 0, stream>>>(s, d);
    }
    {
        Ptr4F s = {{l3_w, l2_w, l1_w, cas_w}};
        Ptr4U d = {{wmA_l3, wmA_l2, wmA_l1, wmA_cas}};
        k_swz_wmA4<<<dim3(CDIV(9216, 256), 4), 256, 0, stream>>>(s, d);
    }

    // ---- input conversions ----
    {
        Ptr4F s = {{L1_off, offset, L1_fea, nullptr}};
        Ptr4U d = {{offn_l1, offn_cas, xn_l1, nullptr}};
        k_cvt_nhwc<<<dim3(CDIV(B * 32 * HW1, 256), 3), 256, 0, stream>>>(s, d, HW1, B);
    }
    {
        Ptr4F s = {{L2_off, nullptr, nullptr, nullptr}};
        Ptr4U d = {{offn_l2, nullptr, nullptr, nullptr}};
        k_cvt_nhwc<<<dim3(CDIV(B * 32 * HW2, 256), 1), 256, 0, stream>>>(s, d, HW2, B);
    }
    {
        Ptr4F s = {{L3_off, nullptr, nullptr, nullptr}};
        Ptr4U d = {{offn_l3, nullptr, nullptr, nullptr}};
        k_cvt_nhwc<<<dim3(CDIV(B * 32 * HW3, 256), 1), 256, 0, stream>>>(s, d, HW3, B);
    }

    // ---- feature pyramid (MFMA convs, NHWC bf16) ----
    k_conv_mfma<3, 1, 2, true><<<CDIV(B * H2 * 2, 4), 256, 0, stream>>>(
        xn_l1, nullptr, wA_l2c1, b_l2c1, L2a, B, H1, W1, H2, W2);
    k_conv_mfma<3, 1, 1, true><<<CDIV(B * H2 * 2, 4), 256, 0, stream>>>(
        L2a, nullptr, wA_l2c2, b_l2c2, L2n, B, H2, W2, H2, W2);
    k_conv_mfma<3, 1, 2, true><<<CDIV(B * H3 * 1, 4), 256, 0, stream>>>(
        L2n, nullptr, wA_l3c1, b_l3c1, L3a, B, H2, W2, H3, W3);
    k_conv_mfma<3, 1, 1, true><<<CDIV(B * H3 * 1, 4), 256, 0, stream>>>(
        L3a, nullptr, wA_l3c2, b_l3c2, L3n, B, H3, W3, H3, W3);

    // ---- L3 dcn + lrelu ----
    k_dcn_fused<1><<<B * HW3 / 32, 256, 0, stream>>>(
        offn_l3, wswz_l3, l3_om_b, L3n, wmA_l3, l3_b, nullptr, L3f, B, H3, W3);

    // ---- L2 dcn, upsample L3f, fuse ----
    k_dcn_fused<0><<<B * HW2 / 32, 256, 0, stream>>>(
        offn_l2, wswz_l2, l2_om_b, L2n, wmA_l2, l2_b, nullptr, L2f_pre, B, H2, W2);
    k_resize2x_nhwc<<<CDIV(B * HW2 * 4, 256), 256, 0, stream>>>(L3f, L3u, B, H3, W3);
    k_conv_mfma<3, 2, 1, true><<<CDIV(B * H2 * 2, 4), 256, 0, stream>>>(
        L2f_pre, L3u, wA_l2fea, b_l2fea, L2f, B, H2, W2, H2, W2);

    // ---- L1 dcn, upsample L2f, fuse (no act) ----
    k_dcn_fused<0><<<B * HW1 / 32, 256, 0, stream>>>(
        offn_l1, wswz_l1, l1_om_b, xn_l1, wmA_l1, l1_b, nullptr, L1f_pre, B, H1, W1);
    k_resize2x_nhwc<<<CDIV(B * HW1 * 4, 256), 256, 0, stream>>>(L2f, L2u, B, H2, W2);
    k_conv_mfma<4, 2, 1, false><<<CDIV(B * H1 * 3, 4), 256, 0, stream>>>(
        L1f_pre, L2u, wA_l1fea, b_l1fea, L1f, B, H1, W1, H1, W1);

    // ---- cascading dcn + lrelu -> output (fp32 NCHW) ----
    k_dcn_fused<2><<<B * HW1 / 32, 256, 0, stream>>>(
        offn_cas, wswz_cas, cas_om_b, L1f, wmA_cas, cas_b, (float*)d_out, nullptr, B, H1, W1);
}